// Round 9
// baseline (484.057 us; speedup 1.0000x reference)
//
#include <hip/hip_runtime.h>
#include <math.h>

namespace {

using s8v = __attribute__((ext_vector_type(8))) short;
using vf4 = __attribute__((ext_vector_type(4))) float;

constexpr int Bn = 65536;
constexpr int Rn = 64;   // rows per block

// ---- workspace layout (bytes) ----
constexpr size_t OFF_A1H  = 0;        // 33*8*64*8 shorts = 270336 B each
constexpr size_t OFF_A1M  = 270336;
constexpr size_t OFF_A1L  = 540672;   // end 811008
constexpr size_t OFF_C1H  = 811008;   // 8*2*64*8 shorts = 16384 B each
constexpr size_t OFF_C1M  = 827392;
constexpr size_t OFF_C1L  = 843776;   // end 860160
constexpr size_t OFF_C2H  = 860160;   // 2*64*8 shorts = 2048 B each
constexpr size_t OFF_C2M  = 862208;
constexpr size_t OFF_C2L  = 864256;   // end 866304
constexpr size_t OFF_G2H  = 866304;   // 4*2*64*8 shorts = 8192 B each
constexpr size_t OFF_G2M  = 874496;
constexpr size_t OFF_G2L  = 882688;   // end 890880
constexpr size_t OFF_VPK  = 890880;   // float[128][4] = 2048 B
constexpr size_t OFF_UPK  = 892928;   // float[32][2] = 256 B
constexpr size_t OFF_CST  = 893184;   // float[8] = 32 B
constexpr size_t OFF_VPART= 893216;   // float[33][128][4] = 67584 B

__device__ __forceinline__ unsigned short bf16_rn(float f) {
    unsigned u = __float_as_uint(f);
    u += 0x7FFFu + ((u >> 16) & 1u);
    return (unsigned short)(u >> 16);
}
__device__ __forceinline__ float bf16_tof(unsigned short h) {
    return __uint_as_float(((unsigned)h) << 16);
}

union S8U { s8v v; unsigned short u[8]; };
union S8P { s8v v; unsigned u32[4]; };

__device__ __forceinline__ vf4 MFMA(s8v a, s8v b, vf4 c) {
    return __builtin_amdgcn_mfma_f32_16x16x32_bf16(a, b, c, 0, 0, 0);
}

// 6-product accumulate: exact x=(h+m+l), drops only (m,l),(l,m),(l,l) ~ 2^-26
__device__ __forceinline__ void mfma6(vf4& acc, s8v ah, s8v am, s8v al,
                                      s8v bh, s8v bm, s8v bl) {
    acc = MFMA(ah, bh, acc);
    acc = MFMA(ah, bm, acc);
    acc = MFMA(am, bh, acc);
    acc = MFMA(ah, bl, acc);
    acc = MFMA(al, bh, acc);
    acc = MFMA(am, bm, acc);
}

// scalar exact 3-way split (pre-kernels only)
__device__ __forceinline__ void split3(float v, unsigned short& h,
                                       unsigned short& m, unsigned short& l) {
    h = bf16_rn(v);
    const float r = v - bf16_tof(h);
    m = bf16_rn(r);
    const float r2 = r - bf16_tof(m);
    l = bf16_rn(r2);
}

// packed 3-way split of 8 fp32 via v_cvt_pk_bf16_f32 (RNE, == bf16_rn bits)
__device__ __forceinline__ void split3x8(const float* vv, s8v& H, s8v& M, s8v& L) {
    S8P h, m, l;
    #pragma unroll
    for (int p = 0; p < 4; ++p) {
        const float lo = vv[2 * p], hi = vv[2 * p + 1];
        unsigned ph, pm, pl;
        asm("v_cvt_pk_bf16_f32 %0, %1, %2" : "=v"(ph) : "v"(lo), "v"(hi));
        const float rlo = lo - __uint_as_float(ph << 16);
        const float rhi = hi - __uint_as_float(ph & 0xFFFF0000u);
        asm("v_cvt_pk_bf16_f32 %0, %1, %2" : "=v"(pm) : "v"(rlo), "v"(rhi));
        const float slo = rlo - __uint_as_float(pm << 16);
        const float shi = rhi - __uint_as_float(pm & 0xFFFF0000u);
        asm("v_cvt_pk_bf16_f32 %0, %1, %2" : "=v"(pl) : "v"(slo), "v"(shi));
        h.u32[p] = ph; m.u32[p] = pm; l.u32[p] = pl;
    }
    H = h.v; M = m.v; L = l.v;
}

__device__ __forceinline__ float gelu_f(float v) {
    return 0.5f * v * (1.0f + erff(v * 0.70710678118654752440f));
}

__device__ __forceinline__ void red16(float& s) {
    s += __shfl_xor(s, 1, 64); s += __shfl_xor(s, 2, 64);
    s += __shfl_xor(s, 4, 64); s += __shfl_xor(s, 8, 64);
}

// ======================= pre-kernel 1: pack big A (gp1) + V partials ======
__global__ void cag_prek1(const float* __restrict__ gp1_w,
                          const float* __restrict__ en_g, const float* __restrict__ en_b,
                          const float* __restrict__ fn_g, const float* __restrict__ fn_b,
                          char* __restrict__ ws)
{
    const int t = threadIdx.x, ch = blockIdx.x;
    s8v* A1h = (s8v*)(ws + OFF_A1H);
    s8v* A1m = (s8v*)(ws + OFF_A1M);
    s8v* A1l = (s8v*)(ws + OFF_A1L);
    float* Vpart = (float*)(ws + OFF_VPART);

    for (int s = t; s < 512; s += 256) {
        const int nt = s >> 6, lane = s & 63;
        const int n = nt * 16 + (lane & 15);
        const int jb = ch * 32 + 8 * (lane >> 4);
        S8U h, m, lo;
        #pragma unroll
        for (int r = 0; r < 8; ++r) {
            const int j = jb + r;
            const float sc = fn_g[j] * (j < 1024 ? en_g[j] : 1.0f);
            const float a = sc * gp1_w[(size_t)j * 128 + n];
            split3(a, h.u[r], m.u[r], lo.u[r]);
        }
        A1h[(ch * 8 + nt) * 64 + lane] = h.v;
        A1m[(ch * 8 + nt) * 64 + lane] = m.v;
        A1l[(ch * 8 + nt) * 64 + lane] = lo.v;
    }
    if (t < 128) {
        float v1 = 0.f, v2 = 0.f, v3 = 0.f, v4 = 0.f;
        for (int jj = 0; jj < 32; ++jj) {
            const int j = ch * 32 + jj;
            const float wv = gp1_w[(size_t)j * 128 + t];
            const float fg = fn_g[j];
            if (j < 1024) { v1 = fmaf(fg * en_g[j], wv, v1); v2 = fmaf(fg * en_b[j], wv, v2); }
            v3 = fmaf(fg, wv, v3);
            v4 = fmaf(fn_b[j], wv, v4);
        }
        float* p = Vpart + ((size_t)ch * 128 + t) * 4;
        p[0] = v1; p[1] = v2; p[2] = v3; p[3] = v4;
    }
}

// ======================= pre-kernel 2: V reduce, consts, small packs ======
__global__ void cag_prek2(const float* __restrict__ en_g, const float* __restrict__ en_b,
                          const float* __restrict__ cn_g, const float* __restrict__ cn_b,
                          const float* __restrict__ cp1_w, const float* __restrict__ cp1_b,
                          const float* __restrict__ cp2_w, const float* __restrict__ gp2_w,
                          const float* __restrict__ gp1_b,
                          char* __restrict__ ws)
{
    const int t = threadIdx.x, b = blockIdx.x;
    if (b == 0) {
        const float* Vpart = (const float*)(ws + OFF_VPART);
        float* Vpk = (float*)(ws + OFF_VPK);
        float* cst = (float*)(ws + OFF_CST);
        if (t < 128) {
            float v1 = 0.f, v2 = 0.f, v3 = 0.f, v4 = 0.f;
            for (int ch = 0; ch < 33; ++ch) {
                const float* p = Vpart + ((size_t)ch * 128 + t) * 4;
                v1 += p[0]; v2 += p[1]; v3 += p[2]; v4 += p[3];
            }
            v4 += gp1_b[t];
            float* q = Vpk + t * 4;
            q[0] = v1; q[1] = v2; q[2] = v3; q[3] = v4;
        }
        __shared__ float red[256];
        float part[5] = {0.f, 0.f, 0.f, 0.f, 0.f};
        for (int i = t; i < 1024; i += 256) {
            const float g = en_g[i], bb = en_b[i];
            part[0] += g; part[1] += bb; part[2] += g * g; part[3] += g * bb; part[4] += bb * bb;
        }
        for (int f = 0; f < 5; ++f) {
            red[t] = part[f]; __syncthreads();
            for (int s = 128; s > 0; s >>= 1) { if (t < s) red[t] += red[t + s]; __syncthreads(); }
            if (t == 0) cst[f] = red[0];
            __syncthreads();
        }
    } else if (b == 1) {
        s8v* C1h = (s8v*)(ws + OFF_C1H);
        s8v* C1m = (s8v*)(ws + OFF_C1M);
        s8v* C1l = (s8v*)(ws + OFF_C1L);
        float* up = (float*)(ws + OFF_UPK);
        for (int s = t; s < 8 * 2 * 64; s += 256) {
            const int ks = s >> 7, nt = (s >> 6) & 1, lane = s & 63;
            const int n = nt * 16 + (lane & 15);
            const int kb = ks * 32 + 8 * (lane >> 4);
            S8U h, m, lo;
            #pragma unroll
            for (int r = 0; r < 8; ++r) {
                const int k = kb + r;
                const float a = cn_g[k] * cp1_w[k * 32 + n];
                split3(a, h.u[r], m.u[r], lo.u[r]);
            }
            C1h[(ks * 2 + nt) * 64 + lane] = h.v;
            C1m[(ks * 2 + nt) * 64 + lane] = m.v;
            C1l[(ks * 2 + nt) * 64 + lane] = lo.v;
        }
        if (t < 32) {
            float u1 = 0.f, u2 = 0.f;
            for (int c = 0; c < 256; ++c) {
                u1 = fmaf(cn_g[c], cp1_w[c * 32 + t], u1);
                u2 = fmaf(cn_b[c], cp1_w[c * 32 + t], u2);
            }
            up[2 * t] = u1; up[2 * t + 1] = u2 + cp1_b[t];
        }
    } else if (b == 2) {
        s8v* C2h = (s8v*)(ws + OFF_C2H);
        s8v* C2m = (s8v*)(ws + OFF_C2M);
        s8v* C2l = (s8v*)(ws + OFF_C2L);
        if (t < 128) {
            const int nt = t >> 6, lane = t & 63;
            const int n = nt * 16 + (lane & 15);
            const int kb = 8 * (lane >> 4);
            S8U h, m, lo;
            #pragma unroll
            for (int r = 0; r < 8; ++r) {
                const float a = cp2_w[(kb + r) * 32 + n];
                split3(a, h.u[r], m.u[r], lo.u[r]);
            }
            C2h[nt * 64 + lane] = h.v;
            C2m[nt * 64 + lane] = m.v;
            C2l[nt * 64 + lane] = lo.v;
        }
    } else {
        s8v* G2h = (s8v*)(ws + OFF_G2H);
        s8v* G2m = (s8v*)(ws + OFF_G2M);
        s8v* G2l = (s8v*)(ws + OFF_G2L);
        for (int s = t; s < 4 * 2 * 64; s += 256) {
            const int ks = s >> 7, nt = (s >> 6) & 1, lane = s & 63;
            const int n = nt * 16 + (lane & 15);
            const int kb = ks * 32 + 8 * (lane >> 4);
            S8U h, m, lo;
            #pragma unroll
            for (int r = 0; r < 8; ++r) {
                const float a = gp2_w[(kb + r) * 32 + n];
                split3(a, h.u[r], m.u[r], lo.u[r]);
            }
            G2h[(ks * 2 + nt) * 64 + lane] = h.v;
            G2m[(ks * 2 + nt) * 64 + lane] = m.v;
            G2l[(ks * 2 + nt) * 64 + lane] = lo.v;
        }
    }
}

// ============================== main kernel ===============================
__global__ __launch_bounds__(256, 4)
void cag_main(const float* __restrict__ x, const float* __restrict__ ctx,
              const float* __restrict__ en_g, const float* __restrict__ en_b,
              const float* __restrict__ cpn_g, const float* __restrict__ cpn_b,
              const float* __restrict__ cp2_b,
              const float* __restrict__ ln1_g, const float* __restrict__ ln1_b,
              const float* __restrict__ gp2_b,
              const float* __restrict__ ln2_g, const float* __restrict__ ln2_b,
              const float* __restrict__ gp3_w, const float* __restrict__ gp3_b,
              const char* __restrict__ ws, float* __restrict__ out)
{
    __shared__ __attribute__((aligned(16))) char smU[64 * 132 * 4];
    __shared__ float s_sc4[64][4];
    __shared__ float s_cfs[64], s_cfs2[64];

    float (*pbuf)[36]   = (float(*)[36])smU;
    float (*cfnbuf)[36] = (float(*)[36])(smU + 12288);            // 9216 B
    float (*hbuf)[132]  = (float(*)[132])smU;
    float (*ibuf)[36]   = (float(*)[36])smU;
    float (*lbuf)[20]   = (float(*)[20])(smU + 16384);

    const int tid = threadIdx.x;
    const int l = tid & 63, w = tid >> 6;
    const int sg = l >> 4, lr = l & 15;
    const int row0 = blockIdx.x * Rn;

    const s8v* A1h = (const s8v*)(ws + OFF_A1H);
    const s8v* A1m = (const s8v*)(ws + OFF_A1M);
    const s8v* A1l = (const s8v*)(ws + OFF_A1L);
    const s8v* C1h = (const s8v*)(ws + OFF_C1H);
    const s8v* C1m = (const s8v*)(ws + OFF_C1M);
    const s8v* C1l = (const s8v*)(ws + OFF_C1L);
    const s8v* C2h = (const s8v*)(ws + OFF_C2H);
    const s8v* C2m = (const s8v*)(ws + OFF_C2M);
    const s8v* C2l = (const s8v*)(ws + OFF_C2L);
    const s8v* G2h = (const s8v*)(ws + OFF_G2H);
    const s8v* G2m = (const s8v*)(ws + OFF_G2M);
    const s8v* G2l = (const s8v*)(ws + OFF_G2L);
    const float* Vpk = (const float*)(ws + OFF_VPK);
    const float* upk = (const float*)(ws + OFF_UPK);
    const float* cst = (const float*)(ws + OFF_CST);

    // ================= P0: context branch (wave-local MFMA) ================
    {
        const int crow = row0 + 16 * w + lr;
        const float* cb = ctx + (size_t)crow * 256 + 8 * sg;
        float cs = 0.f, cs2 = 0.f;
        vf4 ac0 = {0.f, 0.f, 0.f, 0.f}, ac1 = {0.f, 0.f, 0.f, 0.f};
        #pragma unroll
        for (int ks = 0; ks < 8; ++ks) {
            const float4 a0 = *(const float4*)(cb + ks * 32);
            const float4 a1 = *(const float4*)(cb + ks * 32 + 4);
            const float vv[8] = {a0.x, a0.y, a0.z, a0.w, a1.x, a1.y, a1.z, a1.w};
            #pragma unroll
            for (int j = 0; j < 8; ++j) { cs += vv[j]; cs2 = fmaf(vv[j], vv[j], cs2); }
            s8v ah, am, al;
            split3x8(vv, ah, am, al);
            mfma6(ac0, ah, am, al,
                  C1h[(ks * 2 + 0) * 64 + l], C1m[(ks * 2 + 0) * 64 + l], C1l[(ks * 2 + 0) * 64 + l]);
            mfma6(ac1, ah, am, al,
                  C1h[(ks * 2 + 1) * 64 + l], C1m[(ks * 2 + 1) * 64 + l], C1l[(ks * 2 + 1) * 64 + l]);
        }
        cs += __shfl_xor(cs, 16, 64); cs += __shfl_xor(cs, 32, 64);
        cs2 += __shfl_xor(cs2, 16, 64); cs2 += __shfl_xor(cs2, 32, 64);
        const float cm = cs * (1.f / 256.f);
        const float crr = rsqrtf(cs2 * (1.f / 256.f) - cm * cm + 1e-5f);
        float m_r[4], r_r[4];
        #pragma unroll
        for (int rg = 0; rg < 4; ++rg) {
            const int src = 4 * sg + rg;
            m_r[rg] = __shfl(cm, src, 64);
            r_r[rg] = __shfl(crr, src, 64);
        }
        #pragma unroll
        for (int ntl = 0; ntl < 2; ++ntl) {
            const int c = 16 * ntl + lr;
            const float u1 = upk[2 * c], u2 = upk[2 * c + 1];
            #pragma unroll
            for (int rg = 0; rg < 4; ++rg) {
                const float av = (ntl == 0) ? ac0[rg] : ac1[rg];
                const float a1v = r_r[rg] * av - r_r[rg] * m_r[rg] * u1 + u2;
                pbuf[16 * w + 4 * sg + rg][c] = gelu_f(a1v);
            }
        }
        __syncthreads();
        float pv[8];
        const int prow = 16 * w + lr;
        *(float4*)&pv[0] = *(const float4*)&pbuf[prow][8 * sg];
        *(float4*)&pv[4] = *(const float4*)&pbuf[prow][8 * sg + 4];
        s8v ph, pm_, pl;
        split3x8(pv, ph, pm_, pl);
        vf4 a20 = {0.f, 0.f, 0.f, 0.f}, a21 = {0.f, 0.f, 0.f, 0.f};
        mfma6(a20, ph, pm_, pl, C2h[0 * 64 + l], C2m[0 * 64 + l], C2l[0 * 64 + l]);
        mfma6(a21, ph, pm_, pl, C2h[1 * 64 + l], C2m[1 * 64 + l], C2l[1 * 64 + l]);
        const float cb0 = cp2_b[lr], cb1 = cp2_b[16 + lr];
        const float cg0 = cpn_g[lr], cg1 = cpn_g[16 + lr];
        const float cbb0 = cpn_b[lr], cbb1 = cpn_b[16 + lr];
        __syncthreads();   // pbuf reads done before later aliased use
        #pragma unroll
        for (int rg = 0; rg < 4; ++rg) {
            const float v0 = a20[rg] + cb0, v1 = a21[rg] + cb1;
            float s = v0 + v1, s2 = v0 * v0 + v1 * v1;
            red16(s); red16(s2);
            const float pm = s * (1.f / 32.f);
            const float prs = rsqrtf(s2 * (1.f / 32.f) - pm * pm + 1e-5f);
            const float cn0 = (v0 - pm) * prs * cg0 + cbb0;
            const float cn1 = (v1 - pm) * prs * cg1 + cbb1;
            float t = cn0 + cn1, t2 = cn0 * cn0 + cn1 * cn1;
            red16(t); red16(t2);
            const int rr = 16 * w + 4 * sg + rg;
            if (lr == 0) { s_cfs[rr] = t; s_cfs2[rr] = t2; }
            cfnbuf[rr][lr] = cn0; cfnbuf[rr][16 + lr] = cn1;
        }
    }
    __syncthreads();   // cfn/s_cfs visible (intra-wave use only hereafter)

    // ===== P1: barrier-free GEMM. Wave w owns rows 16w..16w+15, ALL 128 cols
    // Register budget discipline (<=64 arch VGPRs): single B set (12 regs,
    // sched_barrier-fenced per n-tile), depth-2 x ping-pong (16 regs), A 12,
    // stats 6. acc[8] lives in AGPRs.
    vf4 acc[8];
    #pragma unroll
    for (int nt = 0; nt < 8; ++nt) acc[nt] = vf4{0.f, 0.f, 0.f, 0.f};

    float Sx = 0.f, Sxx = 0.f, Sxg = 0.f, Sxg2 = 0.f, Sxgb = 0.f, Sq = 0.f;

    const float* xb = x + (size_t)(row0 + 16 * w + lr) * 1024 + 8 * sg;

    float4 xA0 = *(const float4*)(xb);
    float4 xA1 = *(const float4*)(xb + 4);
    float4 xB0, xB1;

    s8v Ah, Am, Al;

    auto chunk = [&](int ks, const float4& c0, const float4& c1,
                     float4& n0, float4& n1) {
        const int kb = ks * 32 + 8 * sg;
        const float4 g0 = *(const float4*)(en_g + kb);
        const float4 g1 = *(const float4*)(en_g + kb + 4);
        const float4 e0 = *(const float4*)(en_b + kb);
        const float4 e1 = *(const float4*)(en_b + kb + 4);
        {
            const float vv[8] = {c0.x, c0.y, c0.z, c0.w, c1.x, c1.y, c1.z, c1.w};
            const float gg[8] = {g0.x, g0.y, g0.z, g0.w, g1.x, g1.y, g1.z, g1.w};
            const float ee[8] = {e0.x, e0.y, e0.z, e0.w, e1.x, e1.y, e1.z, e1.w};
            #pragma unroll
            for (int j = 0; j < 8; ++j) {
                const float v = vv[j], g = gg[j], b = ee[j];
                Sx += v; Sxx = fmaf(v, v, Sxx);
                const float t = v * g;
                Sxg += t; Sxg2 = fmaf(t, g, Sxg2); Sxgb = fmaf(t, b, Sxgb); Sq = fmaf(t, t, Sq);
            }
            split3x8(vv, Ah, Am, Al);
        }
        const size_t qb = (size_t)(ks * 8) * 64 + l;
        #pragma unroll
        for (int nt = 0; nt < 8; ++nt) {
            const s8v bh = A1h[qb + (size_t)nt * 64];
            const s8v bm = A1m[qb + (size_t)nt * 64];
            const s8v bl = A1l[qb + (size_t)nt * 64];
            mfma6(acc[nt], Ah, Am, Al, bh, bm, bl);
            __builtin_amdgcn_sched_barrier(0);  // pin 1-set B usage (regalloc)
        }
        // HBM prefetch for next chunk, issued after all of this chunk's loads
        if (ks < 31) {
            n0 = *(const float4*)(xb + (ks + 1) * 32);
            n1 = *(const float4*)(xb + (ks + 1) * 32 + 4);
        }
        __builtin_amdgcn_sched_barrier(0);
    };

    #pragma unroll 2
    for (int ks = 0; ks < 32; ks += 2) {
        chunk(ks,     xA0, xA1, xB0, xB1);
        chunk(ks + 1, xB0, xB1, xA0, xA1);
    }

    // ---- finalize row stats -> fused LN scalars (row = 16w+lr, own wave)
    float xrinv;
    {
        float sx = Sx, sxx = Sxx, sxg = Sxg, sxg2 = Sxg2, sxgb = Sxgb, sq = Sq;
        #define RED2(s) { s += __shfl_xor(s, 16, 64); s += __shfl_xor(s, 32, 64); }
        RED2(sx) RED2(sxx) RED2(sxg) RED2(sxg2) RED2(sxgb) RED2(sq)
        #undef RED2
        const float xm = sx * (1.f / 1024.f);
        const float xvar = sxx * (1.f / 1024.f) - xm * xm;
        const float xr = rsqrtf(xvar + 1e-5f);
        xrinv = sqrtf(xvar + 1e-5f);
        const float Gs = cst[0], Bs = cst[1], Sg2c = cst[2], Sgbc = cst[3], Sb2c = cst[4];
        const float Semb = xr * (sxg - xm * Gs) + Bs;
        const float Semb2 = xr * xr * (sq - 2.f * xm * sxg2 + xm * xm * Sg2c)
                          + 2.f * xr * (sxgb - xm * Sgbc) + Sb2c;
        const int rr = 16 * w + lr;
        const float fm = (Semb + s_cfs[rr]) * (1.f / 1056.f);
        const float fvar = (Semb2 + s_cfs2[rr]) * (1.f / 1056.f) - fm * fm;
        const float fr = rsqrtf(fvar + 1e-5f);
        if (sg == 0) {
            s_sc4[rr][0] = fr * xr; s_sc4[rr][1] = -fr * xr * xm;
            s_sc4[rr][2] = fr;      s_sc4[rr][3] = -fr * fm;
        }
    }
    // ---- cf chunk (ks=32): A from cfnbuf (own rows), scaled by sigma
    {
        const int rr = 16 * w + lr;
        float vv[8];
        *(float4*)&vv[0] = *(const float4*)&cfnbuf[rr][8 * sg];
        *(float4*)&vv[4] = *(const float4*)&cfnbuf[rr][8 * sg + 4];
        #pragma unroll
        for (int j = 0; j < 8; ++j) vv[j] *= xrinv;
        split3x8(vv, Ah, Am, Al);
        const size_t qb = (size_t)(32 * 8) * 64 + l;
        #pragma unroll
        for (int nt = 0; nt < 8; ++nt) {
            const s8v bh = A1h[qb + (size_t)nt * 64];
            const s8v bm = A1m[qb + (size_t)nt * 64];
            const s8v bl = A1l[qb + (size_t)nt * 64];
            mfma6(acc[nt], Ah, Am, Al, bh, bm, bl);
            __builtin_amdgcn_sched_barrier(0);
        }
    }
    __syncthreads();   // all waves done reading cfnbuf before hbuf overwrites it

    // ================= epilogue: scalars + wave-local LN1 + gelu -> hbuf ===
    {
        float4 s4[4];
        #pragma unroll
        for (int rg = 0; rg < 4; ++rg)
            s4[rg] = *(const float4*)&s_sc4[16 * w + 4 * sg + rg][0];
        #pragma unroll
        for (int nt = 0; nt < 8; ++nt) {
            const float4 Vc = *(const float4*)&Vpk[(16 * nt + lr) * 4];
            #pragma unroll
            for (int rg = 0; rg < 4; ++rg) {
                acc[nt][rg] = s4[rg].x * acc[nt][rg] + s4[rg].y * Vc.x
                            + s4[rg].z * Vc.y + s4[rg].w * Vc.z + Vc.w;
            }
        }
        float g1c[8], b1c[8];
        #pragma unroll
        for (int nt = 0; nt < 8; ++nt) {
            g1c[nt] = ln1_g[16 * nt + lr];
            b1c[nt] = ln1_b[16 * nt + lr];
        }
        #pragma unroll
        for (int rg = 0; rg < 4; ++rg) {
            float s = 0.f, s2 = 0.f;
            #pragma unroll
            for (int nt = 0; nt < 8; ++nt) {
                const float v = acc[nt][rg];
                s += v; s2 = fmaf(v, v, s2);
            }
            red16(s); red16(s2);
            const float mn = s * (1.f / 128.f);
            const float rs = rsqrtf(s2 * (1.f / 128.f) - mn * mn + 1e-5f);
            #pragma unroll
            for (int nt = 0; nt < 8; ++nt) {
                const float hp = gelu_f((acc[nt][rg] - mn) * rs * g1c[nt] + b1c[nt]);
                hbuf[16 * w + 4 * sg + rg][16 * nt + lr] = hp;
            }
        }
    }
    __syncthreads();

    // ================= P2: gp2 (128->32) + LN2 + gelu ======================
    float iv[2][4];
    {
        vf4 aG0 = {0.f, 0.f, 0.f, 0.f}, aG1 = {0.f, 0.f, 0.f, 0.f};
        const int hrow = 16 * w + lr;
        #pragma unroll
        for (int ks = 0; ks < 4; ++ks) {
            float pv[8];
            *(float4*)&pv[0] = *(const float4*)&hbuf[hrow][ks * 32 + 8 * sg];
            *(float4*)&pv[4] = *(const float4*)&hbuf[hrow][ks * 32 + 8 * sg + 4];
            s8v ah, am, al;
            split3x8(pv, ah, am, al);
            mfma6(aG0, ah, am, al,
                  G2h[(ks * 2 + 0) * 64 + l], G2m[(ks * 2 + 0) * 64 + l], G2l[(ks * 2 + 0) * 64 + l]);
            mfma6(aG1, ah, am, al,
                  G2h[(ks * 2 + 1) * 64 + l], G2m[(ks * 2 + 1) * 64 + l], G2l[(ks * 2 + 1) * 64 + l]);
        }
        const float gb0 = gp2_b[lr], gb1 = gp2_b[16 + lr];
        const float lg0 = ln2_g[lr], lg1 = ln2_g[16 + lr];
        const float lb0 = ln2_b[lr], lb1 = ln2_b[16 + lr];
        #pragma unroll
        for (int rg = 0; rg < 4; ++rg) {
            const float v0 = aG0[rg] + gb0, v1 = aG1[rg] + gb1;
            float s = v0 + v1, s2 = v0 * v0 + v1 * v1;
            red16(s); red16(s2);
            const float mn = s * (1.f / 32.f);
            const float rs = rsqrtf(s2 * (1.f / 32.f) - mn * mn + 1e-5f);
            iv[0][rg] = gelu_f((v0 - mn) * rs * lg0 + lb0);
            iv[1][rg] = gelu_f((v1 - mn) * rs * lg1 + lb1);
        }
    }
    __syncthreads();     // all hbuf reads done before ibuf overwrite
    #pragma unroll
    for (int rg = 0; rg < 4; ++rg) {
        const int rr = 16 * w + 4 * sg + rg;
        ibuf[rr][lr] = iv[0][rg];
        ibuf[rr][16 + lr] = iv[1][rg];
    }
    __syncthreads();

    // ================= P3: gp3 (32->16) + logits + top-2 ===================
    {
        const int r = tid >> 2, e4 = (tid & 3) * 4;
        float a0 = 0.f, a1 = 0.f, a2 = 0.f, a3 = 0.f;
        #pragma unroll 4
        for (int qq = 0; qq < 32; ++qq) {
            const float v = ibuf[r][qq];
            const float4 w3 = *(const float4*)(gp3_w + qq * 16 + e4);
            a0 = fmaf(v, w3.x, a0); a1 = fmaf(v, w3.y, a1);
            a2 = fmaf(v, w3.z, a2); a3 = fmaf(v, w3.w, a3);
        }
        const float4 b3 = *(const float4*)(gp3_b + e4);
        const float4 lg = make_float4(a0 + b3.x, a1 + b3.y, a2 + b3.z, a3 + b3.w);
        float* outl = out + (size_t)Bn * 4;
        *(float4*)(outl + (size_t)(row0 + r) * 16 + e4) = lg;
        *(float4*)&lbuf[r][e4] = lg;
    }
    __syncthreads();
    if (tid < 64) {
        float v[16];
        #pragma unroll
        for (int e = 0; e < 4; ++e) *(float4*)&v[e * 4] = *(const float4*)&lbuf[tid][e * 4];
        int i0 = 0; float v0 = v[0];
        #pragma unroll
        for (int e = 1; e < 16; ++e) if (v[e] > v0) { v0 = v[e]; i0 = e; }
        int i1 = -1; float v1 = -3.4e38f;
        #pragma unroll
        for (int e = 0; e < 16; ++e) if (e != i0 && v[e] > v1) { v1 = v[e]; i1 = e; }
        const float e1 = expf(v1 - v0);
        const float inv = 1.0f / (1.0f + e1);
        const size_t g = (size_t)(row0 + tid);
        out[g * 2 + 0] = inv;
        out[g * 2 + 1] = e1 * inv;
        float* outi = out + (size_t)Bn * 2;
        outi[g * 2 + 0] = (float)i0;
        outi[g * 2 + 1] = (float)i1;
    }
}

} // namespace

extern "C" void kernel_launch(void* const* d_in, const int* in_sizes, int n_in,
                              void* d_out, int out_size, void* d_ws, size_t ws_size,
                              hipStream_t stream) {
    const float* x     = (const float*)d_in[0];
    const float* ctx   = (const float*)d_in[1];
    const float* en_g  = (const float*)d_in[2];
    const float* en_b  = (const float*)d_in[3];
    const float* cn_g  = (const float*)d_in[4];
    const float* cn_b  = (const float*)d_in[5];
    const float* cp1_w = (const float*)d_in[6];
    const float* cp1_b = (const float*)d_in[7];
    const float* cp2_w = (const float*)d_in[8];
    const float* cp2_b = (const float*)d_in[9];
    const float* cpn_g = (const float*)d_in[10];
    const float* cpn_b = (const float*)d_in[11];
    const float* fn_g  = (const float*)d_in[12];
    const float* fn_b  = (const float*)d_in[13];
    const float* gp1_w = (const float*)d_in[14];
    const float* gp1_b = (const float*)d_in[15];
    const float* ln1_g = (const float*)d_in[16];
    const float* ln1_b = (const float*)d_in[17];
    const float* gp2_w = (const float*)d_in[18];
    const float* gp2_b = (const float*)d_in[19];
    const float* ln2_g = (const float*)d_in[20];
    const float* ln2_b = (const float*)d_in[21];
    const float* gp3_w = (const float*)d_in[22];
    const float* gp3_b = (const float*)d_in[23];

    char* ws = (char*)d_ws;
    hipLaunchKernelGGL(cag_prek1, dim3(33), dim3(256), 0, stream,
                       gp1_w, en_g, en_b, fn_g, fn_b, ws);
    hipLaunchKernelGGL(cag_prek2, dim3(4), dim3(256), 0, stream,
                       en_g, en_b, cn_g, cn_b, cp1_w, cp1_b, cp2_w, gp2_w, gp1_b, ws);
    hipLaunchKernelGGL(cag_main, dim3(Bn / Rn), dim3(256), 0, stream,
                       x, ctx, en_g, en_b, cpn_g, cpn_b, cp2_b,
                       ln1_g, ln1_b, gp2_b, ln2_g, ln2_b, gp3_w, gp3_b,
                       ws, (float*)d_out);
}

// Round 10
// 194.508 us; speedup vs baseline: 2.4886x; 2.4886x over previous
//
#include <hip/hip_runtime.h>
#include <math.h>

namespace {

using s8v = __attribute__((ext_vector_type(8))) short;
using vf4 = __attribute__((ext_vector_type(4))) float;

constexpr int Bn = 65536;
constexpr int Rn = 64;   // rows per block

// ---- workspace layout (bytes) ----
constexpr size_t OFF_A1H  = 0;        // 33*8*64*8 shorts = 270336 B each
constexpr size_t OFF_A1M  = 270336;
constexpr size_t OFF_A1L  = 540672;   // end 811008
constexpr size_t OFF_C1H  = 811008;   // 8*2*64*8 shorts = 16384 B each
constexpr size_t OFF_C1M  = 827392;
constexpr size_t OFF_C1L  = 843776;   // end 860160
constexpr size_t OFF_C2H  = 860160;   // 2*64*8 shorts = 2048 B each
constexpr size_t OFF_C2M  = 862208;
constexpr size_t OFF_C2L  = 864256;   // end 866304
constexpr size_t OFF_G2H  = 866304;   // 4*2*64*8 shorts = 8192 B each
constexpr size_t OFF_G2M  = 874496;
constexpr size_t OFF_G2L  = 882688;   // end 890880
constexpr size_t OFF_VPK  = 890880;   // float[128][4] = 2048 B
constexpr size_t OFF_UPK  = 892928;   // float[32][2] = 256 B
constexpr size_t OFF_CST  = 893184;   // float[8] = 32 B
constexpr size_t OFF_VPART= 893216;   // float[33][128][4] = 67584 B

__device__ __forceinline__ unsigned short bf16_rn(float f) {
    unsigned u = __float_as_uint(f);
    u += 0x7FFFu + ((u >> 16) & 1u);
    return (unsigned short)(u >> 16);
}
__device__ __forceinline__ float bf16_tof(unsigned short h) {
    return __uint_as_float(((unsigned)h) << 16);
}

union S8U { s8v v; unsigned short u[8]; };
union S8P { s8v v; unsigned u32[4]; };

__device__ __forceinline__ vf4 MFMA(s8v a, s8v b, vf4 c) {
    return __builtin_amdgcn_mfma_f32_16x16x32_bf16(a, b, c, 0, 0, 0);
}

// 6-product accumulate: exact x=(h+m+l), drops only (m,l),(l,m),(l,l) ~ 2^-26
__device__ __forceinline__ void mfma6(vf4& acc, s8v ah, s8v am, s8v al,
                                      s8v bh, s8v bm, s8v bl) {
    acc = MFMA(ah, bh, acc);
    acc = MFMA(ah, bm, acc);
    acc = MFMA(am, bh, acc);
    acc = MFMA(ah, bl, acc);
    acc = MFMA(al, bh, acc);
    acc = MFMA(am, bm, acc);
}

// scalar exact 3-way split (pre-kernels only)
__device__ __forceinline__ void split3(float v, unsigned short& h,
                                       unsigned short& m, unsigned short& l) {
    h = bf16_rn(v);
    const float r = v - bf16_tof(h);
    m = bf16_rn(r);
    const float r2 = r - bf16_tof(m);
    l = bf16_rn(r2);
}

// packed 3-way split of 8 fp32 via v_cvt_pk_bf16_f32 (RNE, == bf16_rn bits)
__device__ __forceinline__ void split3x8(const float* vv, s8v& H, s8v& M, s8v& L) {
    S8P h, m, l;
    #pragma unroll
    for (int p = 0; p < 4; ++p) {
        const float lo = vv[2 * p], hi = vv[2 * p + 1];
        unsigned ph, pm, pl;
        asm("v_cvt_pk_bf16_f32 %0, %1, %2" : "=v"(ph) : "v"(lo), "v"(hi));
        const float rlo = lo - __uint_as_float(ph << 16);
        const float rhi = hi - __uint_as_float(ph & 0xFFFF0000u);
        asm("v_cvt_pk_bf16_f32 %0, %1, %2" : "=v"(pm) : "v"(rlo), "v"(rhi));
        const float slo = rlo - __uint_as_float(pm << 16);
        const float shi = rhi - __uint_as_float(pm & 0xFFFF0000u);
        asm("v_cvt_pk_bf16_f32 %0, %1, %2" : "=v"(pl) : "v"(slo), "v"(shi));
        h.u32[p] = ph; m.u32[p] = pm; l.u32[p] = pl;
    }
    H = h.v; M = m.v; L = l.v;
}

__device__ __forceinline__ float gelu_f(float v) {
    return 0.5f * v * (1.0f + erff(v * 0.70710678118654752440f));
}

__device__ __forceinline__ void red16(float& s) {
    s += __shfl_xor(s, 1, 64); s += __shfl_xor(s, 2, 64);
    s += __shfl_xor(s, 4, 64); s += __shfl_xor(s, 8, 64);
}

// ======================= pre-kernel 1: pack big A (gp1) + V partials ======
__global__ void cag_prek1(const float* __restrict__ gp1_w,
                          const float* __restrict__ en_g, const float* __restrict__ en_b,
                          const float* __restrict__ fn_g, const float* __restrict__ fn_b,
                          char* __restrict__ ws)
{
    const int t = threadIdx.x, ch = blockIdx.x;
    s8v* A1h = (s8v*)(ws + OFF_A1H);
    s8v* A1m = (s8v*)(ws + OFF_A1M);
    s8v* A1l = (s8v*)(ws + OFF_A1L);
    float* Vpart = (float*)(ws + OFF_VPART);

    for (int s = t; s < 512; s += 256) {
        const int nt = s >> 6, lane = s & 63;
        const int n = nt * 16 + (lane & 15);
        const int jb = ch * 32 + 8 * (lane >> 4);
        S8U h, m, lo;
        #pragma unroll
        for (int r = 0; r < 8; ++r) {
            const int j = jb + r;
            const float sc = fn_g[j] * (j < 1024 ? en_g[j] : 1.0f);
            const float a = sc * gp1_w[(size_t)j * 128 + n];
            split3(a, h.u[r], m.u[r], lo.u[r]);
        }
        A1h[(ch * 8 + nt) * 64 + lane] = h.v;
        A1m[(ch * 8 + nt) * 64 + lane] = m.v;
        A1l[(ch * 8 + nt) * 64 + lane] = lo.v;
    }
    if (t < 128) {
        float v1 = 0.f, v2 = 0.f, v3 = 0.f, v4 = 0.f;
        for (int jj = 0; jj < 32; ++jj) {
            const int j = ch * 32 + jj;
            const float wv = gp1_w[(size_t)j * 128 + t];
            const float fg = fn_g[j];
            if (j < 1024) { v1 = fmaf(fg * en_g[j], wv, v1); v2 = fmaf(fg * en_b[j], wv, v2); }
            v3 = fmaf(fg, wv, v3);
            v4 = fmaf(fn_b[j], wv, v4);
        }
        float* p = Vpart + ((size_t)ch * 128 + t) * 4;
        p[0] = v1; p[1] = v2; p[2] = v3; p[3] = v4;
    }
}

// ======================= pre-kernel 2: V reduce, consts, small packs ======
__global__ void cag_prek2(const float* __restrict__ en_g, const float* __restrict__ en_b,
                          const float* __restrict__ cn_g, const float* __restrict__ cn_b,
                          const float* __restrict__ cp1_w, const float* __restrict__ cp1_b,
                          const float* __restrict__ cp2_w, const float* __restrict__ gp2_w,
                          const float* __restrict__ gp1_b,
                          char* __restrict__ ws)
{
    const int t = threadIdx.x, b = blockIdx.x;
    if (b == 0) {
        const float* Vpart = (const float*)(ws + OFF_VPART);
        float* Vpk = (float*)(ws + OFF_VPK);
        float* cst = (float*)(ws + OFF_CST);
        if (t < 128) {
            float v1 = 0.f, v2 = 0.f, v3 = 0.f, v4 = 0.f;
            for (int ch = 0; ch < 33; ++ch) {
                const float* p = Vpart + ((size_t)ch * 128 + t) * 4;
                v1 += p[0]; v2 += p[1]; v3 += p[2]; v4 += p[3];
            }
            v4 += gp1_b[t];
            float* q = Vpk + t * 4;
            q[0] = v1; q[1] = v2; q[2] = v3; q[3] = v4;
        }
        __shared__ float red[256];
        float part[5] = {0.f, 0.f, 0.f, 0.f, 0.f};
        for (int i = t; i < 1024; i += 256) {
            const float g = en_g[i], bb = en_b[i];
            part[0] += g; part[1] += bb; part[2] += g * g; part[3] += g * bb; part[4] += bb * bb;
        }
        for (int f = 0; f < 5; ++f) {
            red[t] = part[f]; __syncthreads();
            for (int s = 128; s > 0; s >>= 1) { if (t < s) red[t] += red[t + s]; __syncthreads(); }
            if (t == 0) cst[f] = red[0];
            __syncthreads();
        }
    } else if (b == 1) {
        s8v* C1h = (s8v*)(ws + OFF_C1H);
        s8v* C1m = (s8v*)(ws + OFF_C1M);
        s8v* C1l = (s8v*)(ws + OFF_C1L);
        float* up = (float*)(ws + OFF_UPK);
        for (int s = t; s < 8 * 2 * 64; s += 256) {
            const int ks = s >> 7, nt = (s >> 6) & 1, lane = s & 63;
            const int n = nt * 16 + (lane & 15);
            const int kb = ks * 32 + 8 * (lane >> 4);
            S8U h, m, lo;
            #pragma unroll
            for (int r = 0; r < 8; ++r) {
                const int k = kb + r;
                const float a = cn_g[k] * cp1_w[k * 32 + n];
                split3(a, h.u[r], m.u[r], lo.u[r]);
            }
            C1h[(ks * 2 + nt) * 64 + lane] = h.v;
            C1m[(ks * 2 + nt) * 64 + lane] = m.v;
            C1l[(ks * 2 + nt) * 64 + lane] = lo.v;
        }
        if (t < 32) {
            float u1 = 0.f, u2 = 0.f;
            for (int c = 0; c < 256; ++c) {
                u1 = fmaf(cn_g[c], cp1_w[c * 32 + t], u1);
                u2 = fmaf(cn_b[c], cp1_w[c * 32 + t], u2);
            }
            up[2 * t] = u1; up[2 * t + 1] = u2 + cp1_b[t];
        }
    } else if (b == 2) {
        s8v* C2h = (s8v*)(ws + OFF_C2H);
        s8v* C2m = (s8v*)(ws + OFF_C2M);
        s8v* C2l = (s8v*)(ws + OFF_C2L);
        if (t < 128) {
            const int nt = t >> 6, lane = t & 63;
            const int n = nt * 16 + (lane & 15);
            const int kb = 8 * (lane >> 4);
            S8U h, m, lo;
            #pragma unroll
            for (int r = 0; r < 8; ++r) {
                const float a = cp2_w[(kb + r) * 32 + n];
                split3(a, h.u[r], m.u[r], lo.u[r]);
            }
            C2h[nt * 64 + lane] = h.v;
            C2m[nt * 64 + lane] = m.v;
            C2l[nt * 64 + lane] = lo.v;
        }
    } else {
        s8v* G2h = (s8v*)(ws + OFF_G2H);
        s8v* G2m = (s8v*)(ws + OFF_G2M);
        s8v* G2l = (s8v*)(ws + OFF_G2L);
        for (int s = t; s < 4 * 2 * 64; s += 256) {
            const int ks = s >> 7, nt = (s >> 6) & 1, lane = s & 63;
            const int n = nt * 16 + (lane & 15);
            const int kb = ks * 32 + 8 * (lane >> 4);
            S8U h, m, lo;
            #pragma unroll
            for (int r = 0; r < 8; ++r) {
                const float a = gp2_w[(kb + r) * 32 + n];
                split3(a, h.u[r], m.u[r], lo.u[r]);
            }
            G2h[(ks * 2 + nt) * 64 + lane] = h.v;
            G2m[(ks * 2 + nt) * 64 + lane] = m.v;
            G2l[(ks * 2 + nt) * 64 + lane] = lo.v;
        }
    }
}

// ============================== main kernel ===============================
__global__ __launch_bounds__(256, 4)
void cag_main(const float* __restrict__ x, const float* __restrict__ ctx,
              const float* __restrict__ en_g, const float* __restrict__ en_b,
              const float* __restrict__ cpn_g, const float* __restrict__ cpn_b,
              const float* __restrict__ cp2_b,
              const float* __restrict__ ln1_g, const float* __restrict__ ln1_b,
              const float* __restrict__ gp2_b,
              const float* __restrict__ ln2_g, const float* __restrict__ ln2_b,
              const float* __restrict__ gp3_w, const float* __restrict__ gp3_b,
              const char* __restrict__ ws, float* __restrict__ out)
{
    // aliased region (33792 B): pbuf(P0)@0 / fragA@0 + cfnbuf@12288 (P1) /
    // hbuf(epi)@0 / ibuf@0, lbuf@16384 (P2/P3)
    __shared__ __attribute__((aligned(16))) char smU[64 * 132 * 4];
    __shared__ float s_sc4[64][4];
    __shared__ float part_s[4][64];
    __shared__ float part_s2[4][64];
    __shared__ float s_ln1[64][2];
    __shared__ float s_cfs[64], s_cfs2[64];

    short (*fragA)[4][64][8] = (short(*)[4][64][8])smU;           // [3][4][64][8] = 12288 B
    float (*cfnbuf)[36] = (float(*)[36])(smU + 12288);            // 9216 B
    float (*pbuf)[36]   = (float(*)[36])smU;
    float (*hbuf)[132]  = (float(*)[132])smU;
    float (*ibuf)[36]   = (float(*)[36])smU;
    float (*lbuf)[20]   = (float(*)[20])(smU + 16384);

    const int tid = threadIdx.x;
    const int l = tid & 63, w = tid >> 6;
    const int sg = l >> 4, lr = l & 15;
    const int row0 = blockIdx.x * Rn;

    const s8v* A1h = (const s8v*)(ws + OFF_A1H);
    const s8v* A1m = (const s8v*)(ws + OFF_A1M);
    const s8v* A1l = (const s8v*)(ws + OFF_A1L);
    const s8v* C1h = (const s8v*)(ws + OFF_C1H);
    const s8v* C1m = (const s8v*)(ws + OFF_C1M);
    const s8v* C1l = (const s8v*)(ws + OFF_C1L);
    const s8v* C2h = (const s8v*)(ws + OFF_C2H);
    const s8v* C2m = (const s8v*)(ws + OFF_C2M);
    const s8v* C2l = (const s8v*)(ws + OFF_C2L);
    const s8v* G2h = (const s8v*)(ws + OFF_G2H);
    const s8v* G2m = (const s8v*)(ws + OFF_G2M);
    const s8v* G2l = (const s8v*)(ws + OFF_G2L);
    const float* Vpk = (const float*)(ws + OFF_VPK);
    const float* upk = (const float*)(ws + OFF_UPK);
    const float* cst = (const float*)(ws + OFF_CST);

    // ================= P0: context branch (wave-local MFMA) ================
    {
        const int crow = row0 + 16 * w + lr;
        const float* cb = ctx + (size_t)crow * 256 + 8 * sg;
        float cs = 0.f, cs2 = 0.f;
        vf4 ac0 = {0.f, 0.f, 0.f, 0.f}, ac1 = {0.f, 0.f, 0.f, 0.f};
        #pragma unroll
        for (int ks = 0; ks < 8; ++ks) {
            const float4 a0 = *(const float4*)(cb + ks * 32);
            const float4 a1 = *(const float4*)(cb + ks * 32 + 4);
            const float vv[8] = {a0.x, a0.y, a0.z, a0.w, a1.x, a1.y, a1.z, a1.w};
            #pragma unroll
            for (int j = 0; j < 8; ++j) { cs += vv[j]; cs2 = fmaf(vv[j], vv[j], cs2); }
            s8v ah, am, al;
            split3x8(vv, ah, am, al);
            mfma6(ac0, ah, am, al,
                  C1h[(ks * 2 + 0) * 64 + l], C1m[(ks * 2 + 0) * 64 + l], C1l[(ks * 2 + 0) * 64 + l]);
            mfma6(ac1, ah, am, al,
                  C1h[(ks * 2 + 1) * 64 + l], C1m[(ks * 2 + 1) * 64 + l], C1l[(ks * 2 + 1) * 64 + l]);
        }
        cs += __shfl_xor(cs, 16, 64); cs += __shfl_xor(cs, 32, 64);
        cs2 += __shfl_xor(cs2, 16, 64); cs2 += __shfl_xor(cs2, 32, 64);
        const float cm = cs * (1.f / 256.f);
        const float crr = rsqrtf(cs2 * (1.f / 256.f) - cm * cm + 1e-5f);
        float m_r[4], r_r[4];
        #pragma unroll
        for (int rg = 0; rg < 4; ++rg) {
            const int src = 4 * sg + rg;
            m_r[rg] = __shfl(cm, src, 64);
            r_r[rg] = __shfl(crr, src, 64);
        }
        #pragma unroll
        for (int ntl = 0; ntl < 2; ++ntl) {
            const int c = 16 * ntl + lr;
            const float u1 = upk[2 * c], u2 = upk[2 * c + 1];
            #pragma unroll
            for (int rg = 0; rg < 4; ++rg) {
                const float av = (ntl == 0) ? ac0[rg] : ac1[rg];
                const float a1v = r_r[rg] * av - r_r[rg] * m_r[rg] * u1 + u2;
                pbuf[16 * w + 4 * sg + rg][c] = gelu_f(a1v);
            }
        }
        __syncthreads();
        float pv[8];
        const int prow = 16 * w + lr;
        *(float4*)&pv[0] = *(const float4*)&pbuf[prow][8 * sg];
        *(float4*)&pv[4] = *(const float4*)&pbuf[prow][8 * sg + 4];
        s8v ph, pm_, pl;
        split3x8(pv, ph, pm_, pl);
        vf4 a20 = {0.f, 0.f, 0.f, 0.f}, a21 = {0.f, 0.f, 0.f, 0.f};
        mfma6(a20, ph, pm_, pl, C2h[0 * 64 + l], C2m[0 * 64 + l], C2l[0 * 64 + l]);
        mfma6(a21, ph, pm_, pl, C2h[1 * 64 + l], C2m[1 * 64 + l], C2l[1 * 64 + l]);
        const float cb0 = cp2_b[lr], cb1 = cp2_b[16 + lr];
        const float cg0 = cpn_g[lr], cg1 = cpn_g[16 + lr];
        const float cbb0 = cpn_b[lr], cbb1 = cpn_b[16 + lr];
        __syncthreads();
        #pragma unroll
        for (int rg = 0; rg < 4; ++rg) {
            const float v0 = a20[rg] + cb0, v1 = a21[rg] + cb1;
            float s = v0 + v1, s2 = v0 * v0 + v1 * v1;
            red16(s); red16(s2);
            const float pm = s * (1.f / 32.f);
            const float prs = rsqrtf(s2 * (1.f / 32.f) - pm * pm + 1e-5f);
            const float cn0 = (v0 - pm) * prs * cg0 + cbb0;
            const float cn1 = (v1 - pm) * prs * cg1 + cbb1;
            float t = cn0 + cn1, t2 = cn0 * cn0 + cn1 * cn1;
            red16(t); red16(t2);
            const int rr = 16 * w + 4 * sg + rg;
            if (lr == 0) { s_cfs[rr] = t; s_cfs2[rr] = t2; }
            cfnbuf[rr][lr] = cn0; cfnbuf[rr][16 + lr] = cn1;
        }
    }
    __syncthreads();   // cfn/s_cfs visible; pbuf dead; fragA region free

    // ================= P1: phase-split GEMM over K=1056 ====================
    vf4 acc[4][2];
    #pragma unroll
    for (int mt = 0; mt < 4; ++mt) { acc[mt][0] = vf4{0.f,0.f,0.f,0.f}; acc[mt][1] = vf4{0.f,0.f,0.f,0.f}; }

    float Sx = 0.f, Sxx = 0.f, Sxg = 0.f, Sxg2 = 0.f, Sxgb = 0.f, Sq = 0.f;

    const float* xb = x + (size_t)(row0 + 16 * w + lr) * 1024 + 8 * sg;
    const int nt0 = 2 * w;

    float4 xc0 = *(const float4*)(xb);
    float4 xc1 = *(const float4*)(xb + 4);
    float4 xn0, xn1;

    #pragma unroll 1
    for (int ks = 0; ks <= 32; ++ks) {
        // ---------- stage phase ----------
        // B loads for THIS ks (L2) — in flight across stage + barrier
        const size_t q = (size_t)((ks * 8 + nt0) * 64 + l);
        const s8v B0h = A1h[q],      B0m = A1m[q],      B0l = A1l[q];
        const s8v B1h = A1h[q + 64], B1m = A1m[q + 64], B1l = A1l[q + 64];
        // x prefetch for ks+1 (HBM) — in flight across stage + mfma phases
        if (ks < 31) {
            xn0 = *(const float4*)(xb + (ks + 1) * 32);
            xn1 = *(const float4*)(xb + (ks + 1) * 32 + 4);
        }
        if (ks < 32) {
            const int kb = ks * 32 + 8 * sg;
            const float4 g0 = *(const float4*)(en_g + kb);
            const float4 g1 = *(const float4*)(en_g + kb + 4);
            const float4 e0 = *(const float4*)(en_b + kb);
            const float4 e1 = *(const float4*)(en_b + kb + 4);
            const float vv[8] = {xc0.x, xc0.y, xc0.z, xc0.w, xc1.x, xc1.y, xc1.z, xc1.w};
            const float gg[8] = {g0.x, g0.y, g0.z, g0.w, g1.x, g1.y, g1.z, g1.w};
            const float ee[8] = {e0.x, e0.y, e0.z, e0.w, e1.x, e1.y, e1.z, e1.w};
            #pragma unroll
            for (int j = 0; j < 8; ++j) {
                const float v = vv[j], g = gg[j], b = ee[j];
                Sx += v; Sxx = fmaf(v, v, Sxx);
                const float t = v * g;
                Sxg += t; Sxg2 = fmaf(t, g, Sxg2); Sxgb = fmaf(t, b, Sxgb); Sq = fmaf(t, t, Sq);
            }
            s8v H, M, L;
            split3x8(vv, H, M, L);
            *(s8v*)&fragA[0][w][l][0] = H;
            *(s8v*)&fragA[1][w][l][0] = M;
            *(s8v*)&fragA[2][w][l][0] = L;
        } else {
            // finalize row stats + fused LN scalars
            float sx = Sx, sxx = Sxx, sxg = Sxg, sxg2 = Sxg2, sxgb = Sxgb, sq = Sq;
            #define RED2(s) { s += __shfl_xor(s, 16, 64); s += __shfl_xor(s, 32, 64); }
            RED2(sx) RED2(sxx) RED2(sxg) RED2(sxg2) RED2(sxgb) RED2(sq)
            #undef RED2
            const float xm = sx * (1.f / 1024.f);
            const float xvar = sxx * (1.f / 1024.f) - xm * xm;
            const float xr = rsqrtf(xvar + 1e-5f);
            const float xrinv = sqrtf(xvar + 1e-5f);
            const float Gs = cst[0], Bs = cst[1], Sg2c = cst[2], Sgbc = cst[3], Sb2c = cst[4];
            const float Semb = xr * (sxg - xm * Gs) + Bs;
            const float Semb2 = xr * xr * (sq - 2.f * xm * sxg2 + xm * xm * Sg2c)
                              + 2.f * xr * (sxgb - xm * Sgbc) + Sb2c;
            const int rr = 16 * w + lr;
            const float fm = (Semb + s_cfs[rr]) * (1.f / 1056.f);
            const float fvar = (Semb2 + s_cfs2[rr]) * (1.f / 1056.f) - fm * fm;
            const float fr = rsqrtf(fvar + 1e-5f);
            if (sg == 0) {
                s_sc4[rr][0] = fr * xr; s_sc4[rr][1] = -fr * xr * xm;
                s_sc4[rr][2] = fr;      s_sc4[rr][3] = -fr * fm;
            }
            // stage cf chunk (k=1024..1055), scaled by this row's sigma
            float vv[8];
            *(float4*)&vv[0] = *(const float4*)&cfnbuf[rr][8 * sg];
            *(float4*)&vv[4] = *(const float4*)&cfnbuf[rr][8 * sg + 4];
            #pragma unroll
            for (int j = 0; j < 8; ++j) vv[j] *= xrinv;
            s8v H, M, L;
            split3x8(vv, H, M, L);
            *(s8v*)&fragA[0][w][l][0] = H;
            *(s8v*)&fragA[1][w][l][0] = M;
            *(s8v*)&fragA[2][w][l][0] = L;
        }
        // flush LDS writes, barrier; global loads stay in flight (no vmcnt drain)
        asm volatile("s_waitcnt lgkmcnt(0)\n\ts_barrier" ::: "memory");

        // ---------- mfma phase ----------
        __builtin_amdgcn_s_setprio(1);
        #pragma unroll
        for (int mt = 0; mt < 4; ++mt) {
            const s8v ah = *(const s8v*)&fragA[0][mt][l][0];
            const s8v am = *(const s8v*)&fragA[1][mt][l][0];
            const s8v al = *(const s8v*)&fragA[2][mt][l][0];
            mfma6(acc[mt][0], ah, am, al, B0h, B0m, B0l);
            mfma6(acc[mt][1], ah, am, al, B1h, B1m, B1l);
        }
        __builtin_amdgcn_s_setprio(0);
        asm volatile("s_barrier" ::: "memory");
        xc0 = xn0; xc1 = xn1;
    }

    // ================= epilogue: scalars + LN1 + gelu -> hbuf ==============
    {
        const int tc0 = 16 * (2 * w) + lr, tc1 = 16 * (2 * w + 1) + lr;
        float4 Vc[2];
        Vc[0] = *(const float4*)&Vpk[tc0 * 4];
        Vc[1] = *(const float4*)&Vpk[tc1 * 4];
        #pragma unroll
        for (int mt = 0; mt < 4; ++mt) {
            #pragma unroll
            for (int rg = 0; rg < 4; ++rg) {
                const float4 sc = *(const float4*)&s_sc4[16 * mt + 4 * sg + rg][0];
                #pragma unroll
                for (int ntl = 0; ntl < 2; ++ntl) {
                    acc[mt][ntl][rg] = sc.x * acc[mt][ntl][rg] + sc.y * Vc[ntl].x
                                     + sc.z * Vc[ntl].y + sc.w * Vc[ntl].z + Vc[ntl].w;
                }
            }
        }
        #pragma unroll
        for (int mt = 0; mt < 4; ++mt) {
            #pragma unroll
            for (int rg = 0; rg < 4; ++rg) {
                const float v0 = acc[mt][0][rg], v1 = acc[mt][1][rg];
                float s = v0 + v1, s2 = v0 * v0 + v1 * v1;
                red16(s); red16(s2);
                if (lr == 0) {
                    const int rr = 16 * mt + 4 * sg + rg;
                    part_s[w][rr] = s; part_s2[w][rr] = s2;
                }
            }
        }
        __syncthreads();
        if (tid < 64) {
            const float s = part_s[0][tid] + part_s[1][tid] + part_s[2][tid] + part_s[3][tid];
            const float s2 = part_s2[0][tid] + part_s2[1][tid] + part_s2[2][tid] + part_s2[3][tid];
            const float mn = s * (1.f / 128.f);
            s_ln1[tid][0] = mn;
            s_ln1[tid][1] = rsqrtf(s2 * (1.f / 128.f) - mn * mn + 1e-5f);
        }
        __syncthreads();
        float g1c[2], b1c[2];
        g1c[0] = ln1_g[tc0]; b1c[0] = ln1_b[tc0];
        g1c[1] = ln1_g[tc1]; b1c[1] = ln1_b[tc1];
        #pragma unroll
        for (int mt = 0; mt < 4; ++mt) {
            #pragma unroll
            for (int rg = 0; rg < 4; ++rg) {
                const int rr = 16 * mt + 4 * sg + rg;
                const float mn = s_ln1[rr][0], rs = s_ln1[rr][1];
                #pragma unroll
                for (int ntl = 0; ntl < 2; ++ntl) {
                    const float hp = gelu_f((acc[mt][ntl][rg] - mn) * rs * g1c[ntl] + b1c[ntl]);
                    hbuf[rr][16 * (2 * w + ntl) + lr] = hp;
                }
            }
        }
        __syncthreads();
    }

    // ================= P2: gp2 (128->32) + LN2 + gelu ======================
    float iv[2][4];
    {
        vf4 aG0 = {0.f, 0.f, 0.f, 0.f}, aG1 = {0.f, 0.f, 0.f, 0.f};
        const int hrow = 16 * w + lr;
        #pragma unroll
        for (int ks = 0; ks < 4; ++ks) {
            float pv[8];
            *(float4*)&pv[0] = *(const float4*)&hbuf[hrow][ks * 32 + 8 * sg];
            *(float4*)&pv[4] = *(const float4*)&hbuf[hrow][ks * 32 + 8 * sg + 4];
            s8v ah, am, al;
            split3x8(pv, ah, am, al);
            mfma6(aG0, ah, am, al,
                  G2h[(ks * 2 + 0) * 64 + l], G2m[(ks * 2 + 0) * 64 + l], G2l[(ks * 2 + 0) * 64 + l]);
            mfma6(aG1, ah, am, al,
                  G2h[(ks * 2 + 1) * 64 + l], G2m[(ks * 2 + 1) * 64 + l], G2l[(ks * 2 + 1) * 64 + l]);
        }
        const float gb0 = gp2_b[lr], gb1 = gp2_b[16 + lr];
        const float lg0 = ln2_g[lr], lg1 = ln2_g[16 + lr];
        const float lb0 = ln2_b[lr], lb1 = ln2_b[16 + lr];
        #pragma unroll
        for (int rg = 0; rg < 4; ++rg) {
            const float v0 = aG0[rg] + gb0, v1 = aG1[rg] + gb1;
            float s = v0 + v1, s2 = v0 * v0 + v1 * v1;
            red16(s); red16(s2);
            const float mn = s * (1.f / 32.f);
            const float rs = rsqrtf(s2 * (1.f / 32.f) - mn * mn + 1e-5f);
            iv[0][rg] = gelu_f((v0 - mn) * rs * lg0 + lb0);
            iv[1][rg] = gelu_f((v1 - mn) * rs * lg1 + lb1);
        }
    }
    __syncthreads();     // all hbuf reads done before ibuf overwrite
    #pragma unroll
    for (int rg = 0; rg < 4; ++rg) {
        const int rr = 16 * w + 4 * sg + rg;
        ibuf[rr][lr] = iv[0][rg];
        ibuf[rr][16 + lr] = iv[1][rg];
    }
    __syncthreads();

    // ================= P3: gp3 (32->16) + logits + top-2 ===================
    {
        const int r = tid >> 2, e4 = (tid & 3) * 4;
        float a0 = 0.f, a1 = 0.f, a2 = 0.f, a3 = 0.f;
        #pragma unroll 4
        for (int qq = 0; qq < 32; ++qq) {
            const float v = ibuf[r][qq];
            const float4 w3 = *(const float4*)(gp3_w + qq * 16 + e4);
            a0 = fmaf(v, w3.x, a0); a1 = fmaf(v, w3.y, a1);
            a2 = fmaf(v, w3.z, a2); a3 = fmaf(v, w3.w, a3);
        }
        const float4 b3 = *(const float4*)(gp3_b + e4);
        const float4 lg = make_float4(a0 + b3.x, a1 + b3.y, a2 + b3.z, a3 + b3.w);
        float* outl = out + (size_t)Bn * 4;
        *(float4*)(outl + (size_t)(row0 + r) * 16 + e4) = lg;
        *(float4*)&lbuf[r][e4] = lg;
    }
    __syncthreads();
    if (tid < 64) {
        float v[16];
        #pragma unroll
        for (int e = 0; e < 4; ++e) *(float4*)&v[e * 4] = *(const float4*)&lbuf[tid][e * 4];
        int i0 = 0; float v0 = v[0];
        #pragma unroll
        for (int e = 1; e < 16; ++e) if (v[e] > v0) { v0 = v[e]; i0 = e; }
        int i1 = -1; float v1 = -3.4e38f;
        #pragma unroll
        for (int e = 0; e < 16; ++e) if (e != i0 && v[e] > v1) { v1 = v[e]; i1 = e; }
        const float e1 = expf(v1 - v0);
        const float inv = 1.0f / (1.0f + e1);
        const size_t g = (size_t)(row0 + tid);
        out[g * 2 + 0] = inv;
        out[g * 2 + 1] = e1 * inv;
        float* outi = out + (size_t)Bn * 2;
        outi[g * 2 + 0] = (float)i0;
        outi[g * 2 + 1] = (float)i1;
    }
}

} // namespace

extern "C" void kernel_launch(void* const* d_in, const int* in_sizes, int n_in,
                              void* d_out, int out_size, void* d_ws, size_t ws_size,
                              hipStream_t stream) {
    const float* x     = (const float*)d_in[0];
    const float* ctx   = (const float*)d_in[1];
    const float* en_g  = (const float*)d_in[2];
    const float* en_b  = (const float*)d_in[3];
    const float* cn_g  = (const float*)d_in[4];
    const float* cn_b  = (const float*)d_in[5];
    const float* cp1_w = (const float*)d_in[6];
    const float* cp1_b = (const float*)d_in[7];
    const float* cp2_w = (const float*)d_in[8];
    const float* cp2_b = (const float*)d_in[9];
    const float* cpn_g = (const float*)d_in[10];
    const float* cpn_b = (const float*)d_in[11];
    const float* fn_g  = (const float*)d_in[12];
    const float* fn_b  = (const float*)d_in[13];
    const float* gp1_w = (const float*)d_in[14];
    const float* gp1_b = (const float*)d_in[15];
    const float* ln1_g = (const float*)d_in[16];
    const float* ln1_b = (const float*)d_in[17];
    const float* gp2_w = (const float*)d_in[18];
    const float* gp2_b = (const float*)d_in[19];
    const float* ln2_g = (const float*)d_in[20];
    const float* ln2_b = (const float*)d_in[21];
    const float* gp3_w = (const float*)d_in[22];
    const float* gp3_b = (const float*)d_in[23];

    char* ws = (char*)d_ws;
    hipLaunchKernelGGL(cag_prek1, dim3(33), dim3(256), 0, stream,
                       gp1_w, en_g, en_b, fn_g, fn_b, ws);
    hipLaunchKernelGGL(cag_prek2, dim3(4), dim3(256), 0, stream,
                       en_g, en_b, cn_g, cn_b, cp1_w, cp1_b, cp2_w, gp2_w, gp1_b, ws);
    hipLaunchKernelGGL(cag_main, dim3(Bn / Rn), dim3(256), 0, stream,
                       x, ctx, en_g, en_b, cpn_g, cpn_b, cp2_b,
                       ln1_g, ln1_b, gp2_b, ln2_g, ln2_b, gp3_w, gp3_b,
                       ws, (float*)d_out);
}

// Round 11
// 193.452 us; speedup vs baseline: 2.5022x; 1.0055x over previous
//
#include <hip/hip_runtime.h>
#include <math.h>

namespace {

using s8v = __attribute__((ext_vector_type(8))) short;
using vf4 = __attribute__((ext_vector_type(4))) float;

constexpr int Bn = 65536;
constexpr int Rn = 64;   // rows per block

// ---- workspace layout (bytes) ----
constexpr size_t OFF_A1H  = 0;        // 33*8*64*8 shorts = 270336 B each
constexpr size_t OFF_A1M  = 270336;
constexpr size_t OFF_A1L  = 540672;   // end 811008
constexpr size_t OFF_C1H  = 811008;   // 8*2*64*8 shorts = 16384 B each
constexpr size_t OFF_C1M  = 827392;
constexpr size_t OFF_C1L  = 843776;   // end 860160
constexpr size_t OFF_C2H  = 860160;   // 2*64*8 shorts = 2048 B each
constexpr size_t OFF_C2M  = 862208;
constexpr size_t OFF_C2L  = 864256;   // end 866304
constexpr size_t OFF_G2H  = 866304;   // 4*2*64*8 shorts = 8192 B each
constexpr size_t OFF_G2M  = 874496;
constexpr size_t OFF_G2L  = 882688;   // end 890880
constexpr size_t OFF_VPK  = 890880;   // float[128][4] = 2048 B
constexpr size_t OFF_UPK  = 892928;   // float[32][2] = 256 B
constexpr size_t OFF_CST  = 893184;   // float[8] = 32 B
constexpr size_t OFF_VPART= 893216;   // float[33][128][4] = 67584 B

__device__ __forceinline__ unsigned short bf16_rn(float f) {
    unsigned u = __float_as_uint(f);
    u += 0x7FFFu + ((u >> 16) & 1u);
    return (unsigned short)(u >> 16);
}
__device__ __forceinline__ float bf16_tof(unsigned short h) {
    return __uint_as_float(((unsigned)h) << 16);
}

union S8U { s8v v; unsigned short u[8]; };
union S8P { s8v v; unsigned u32[4]; };

__device__ __forceinline__ vf4 MFMA(s8v a, s8v b, vf4 c) {
    return __builtin_amdgcn_mfma_f32_16x16x32_bf16(a, b, c, 0, 0, 0);
}

// 6-product accumulate: exact x=(h+m+l), drops only (m,l),(l,m),(l,l) ~ 2^-26
__device__ __forceinline__ void mfma6(vf4& acc, s8v ah, s8v am, s8v al,
                                      s8v bh, s8v bm, s8v bl) {
    acc = MFMA(ah, bh, acc);
    acc = MFMA(ah, bm, acc);
    acc = MFMA(am, bh, acc);
    acc = MFMA(ah, bl, acc);
    acc = MFMA(al, bh, acc);
    acc = MFMA(am, bm, acc);
}

// scalar exact 3-way split (pre-kernels only)
__device__ __forceinline__ void split3(float v, unsigned short& h,
                                       unsigned short& m, unsigned short& l) {
    h = bf16_rn(v);
    const float r = v - bf16_tof(h);
    m = bf16_rn(r);
    const float r2 = r - bf16_tof(m);
    l = bf16_rn(r2);
}

// packed 3-way split of 8 fp32 via v_cvt_pk_bf16_f32 (RNE, == bf16_rn bits)
__device__ __forceinline__ void split3x8(const float* vv, s8v& H, s8v& M, s8v& L) {
    S8P h, m, l;
    #pragma unroll
    for (int p = 0; p < 4; ++p) {
        const float lo = vv[2 * p], hi = vv[2 * p + 1];
        unsigned ph, pm, pl;
        asm("v_cvt_pk_bf16_f32 %0, %1, %2" : "=v"(ph) : "v"(lo), "v"(hi));
        const float rlo = lo - __uint_as_float(ph << 16);
        const float rhi = hi - __uint_as_float(ph & 0xFFFF0000u);
        asm("v_cvt_pk_bf16_f32 %0, %1, %2" : "=v"(pm) : "v"(rlo), "v"(rhi));
        const float slo = rlo - __uint_as_float(pm << 16);
        const float shi = rhi - __uint_as_float(pm & 0xFFFF0000u);
        asm("v_cvt_pk_bf16_f32 %0, %1, %2" : "=v"(pl) : "v"(slo), "v"(shi));
        h.u32[p] = ph; m.u32[p] = pm; l.u32[p] = pl;
    }
    H = h.v; M = m.v; L = l.v;
}

__device__ __forceinline__ float gelu_f(float v) {
    return 0.5f * v * (1.0f + erff(v * 0.70710678118654752440f));
}

__device__ __forceinline__ void red16(float& s) {
    s += __shfl_xor(s, 1, 64); s += __shfl_xor(s, 2, 64);
    s += __shfl_xor(s, 4, 64); s += __shfl_xor(s, 8, 64);
}

// ======================= pre-kernel 1: pack big A (gp1) + V partials ======
__global__ void cag_prek1(const float* __restrict__ gp1_w,
                          const float* __restrict__ en_g, const float* __restrict__ en_b,
                          const float* __restrict__ fn_g, const float* __restrict__ fn_b,
                          char* __restrict__ ws)
{
    const int t = threadIdx.x, ch = blockIdx.x;
    s8v* A1h = (s8v*)(ws + OFF_A1H);
    s8v* A1m = (s8v*)(ws + OFF_A1M);
    s8v* A1l = (s8v*)(ws + OFF_A1L);
    float* Vpart = (float*)(ws + OFF_VPART);

    for (int s = t; s < 512; s += 256) {
        const int nt = s >> 6, lane = s & 63;
        const int n = nt * 16 + (lane & 15);
        const int jb = ch * 32 + 8 * (lane >> 4);
        S8U h, m, lo;
        #pragma unroll
        for (int r = 0; r < 8; ++r) {
            const int j = jb + r;
            const float sc = fn_g[j] * (j < 1024 ? en_g[j] : 1.0f);
            const float a = sc * gp1_w[(size_t)j * 128 + n];
            split3(a, h.u[r], m.u[r], lo.u[r]);
        }
        A1h[(ch * 8 + nt) * 64 + lane] = h.v;
        A1m[(ch * 8 + nt) * 64 + lane] = m.v;
        A1l[(ch * 8 + nt) * 64 + lane] = lo.v;
    }
    if (t < 128) {
        float v1 = 0.f, v2 = 0.f, v3 = 0.f, v4 = 0.f;
        for (int jj = 0; jj < 32; ++jj) {
            const int j = ch * 32 + jj;
            const float wv = gp1_w[(size_t)j * 128 + t];
            const float fg = fn_g[j];
            if (j < 1024) { v1 = fmaf(fg * en_g[j], wv, v1); v2 = fmaf(fg * en_b[j], wv, v2); }
            v3 = fmaf(fg, wv, v3);
            v4 = fmaf(fn_b[j], wv, v4);
        }
        float* p = Vpart + ((size_t)ch * 128 + t) * 4;
        p[0] = v1; p[1] = v2; p[2] = v3; p[3] = v4;
    }
}

// ======================= pre-kernel 2: V reduce, consts, small packs ======
__global__ void cag_prek2(const float* __restrict__ en_g, const float* __restrict__ en_b,
                          const float* __restrict__ cn_g, const float* __restrict__ cn_b,
                          const float* __restrict__ cp1_w, const float* __restrict__ cp1_b,
                          const float* __restrict__ cp2_w, const float* __restrict__ gp2_w,
                          const float* __restrict__ gp1_b,
                          char* __restrict__ ws)
{
    const int t = threadIdx.x, b = blockIdx.x;
    if (b == 0) {
        const float* Vpart = (const float*)(ws + OFF_VPART);
        float* Vpk = (float*)(ws + OFF_VPK);
        float* cst = (float*)(ws + OFF_CST);
        if (t < 128) {
            float v1 = 0.f, v2 = 0.f, v3 = 0.f, v4 = 0.f;
            for (int ch = 0; ch < 33; ++ch) {
                const float* p = Vpart + ((size_t)ch * 128 + t) * 4;
                v1 += p[0]; v2 += p[1]; v3 += p[2]; v4 += p[3];
            }
            v4 += gp1_b[t];
            float* q = Vpk + t * 4;
            q[0] = v1; q[1] = v2; q[2] = v3; q[3] = v4;
        }
        __shared__ float red[256];
        float part[5] = {0.f, 0.f, 0.f, 0.f, 0.f};
        for (int i = t; i < 1024; i += 256) {
            const float g = en_g[i], bb = en_b[i];
            part[0] += g; part[1] += bb; part[2] += g * g; part[3] += g * bb; part[4] += bb * bb;
        }
        for (int f = 0; f < 5; ++f) {
            red[t] = part[f]; __syncthreads();
            for (int s = 128; s > 0; s >>= 1) { if (t < s) red[t] += red[t + s]; __syncthreads(); }
            if (t == 0) cst[f] = red[0];
            __syncthreads();
        }
    } else if (b == 1) {
        s8v* C1h = (s8v*)(ws + OFF_C1H);
        s8v* C1m = (s8v*)(ws + OFF_C1M);
        s8v* C1l = (s8v*)(ws + OFF_C1L);
        float* up = (float*)(ws + OFF_UPK);
        for (int s = t; s < 8 * 2 * 64; s += 256) {
            const int ks = s >> 7, nt = (s >> 6) & 1, lane = s & 63;
            const int n = nt * 16 + (lane & 15);
            const int kb = ks * 32 + 8 * (lane >> 4);
            S8U h, m, lo;
            #pragma unroll
            for (int r = 0; r < 8; ++r) {
                const int k = kb + r;
                const float a = cn_g[k] * cp1_w[k * 32 + n];
                split3(a, h.u[r], m.u[r], lo.u[r]);
            }
            C1h[(ks * 2 + nt) * 64 + lane] = h.v;
            C1m[(ks * 2 + nt) * 64 + lane] = m.v;
            C1l[(ks * 2 + nt) * 64 + lane] = lo.v;
        }
        if (t < 32) {
            float u1 = 0.f, u2 = 0.f;
            for (int c = 0; c < 256; ++c) {
                u1 = fmaf(cn_g[c], cp1_w[c * 32 + t], u1);
                u2 = fmaf(cn_b[c], cp1_w[c * 32 + t], u2);
            }
            up[2 * t] = u1; up[2 * t + 1] = u2 + cp1_b[t];
        }
    } else if (b == 2) {
        s8v* C2h = (s8v*)(ws + OFF_C2H);
        s8v* C2m = (s8v*)(ws + OFF_C2M);
        s8v* C2l = (s8v*)(ws + OFF_C2L);
        if (t < 128) {
            const int nt = t >> 6, lane = t & 63;
            const int n = nt * 16 + (lane & 15);
            const int kb = 8 * (lane >> 4);
            S8U h, m, lo;
            #pragma unroll
            for (int r = 0; r < 8; ++r) {
                const float a = cp2_w[(kb + r) * 32 + n];
                split3(a, h.u[r], m.u[r], lo.u[r]);
            }
            C2h[nt * 64 + lane] = h.v;
            C2m[nt * 64 + lane] = m.v;
            C2l[nt * 64 + lane] = lo.v;
        }
    } else {
        s8v* G2h = (s8v*)(ws + OFF_G2H);
        s8v* G2m = (s8v*)(ws + OFF_G2M);
        s8v* G2l = (s8v*)(ws + OFF_G2L);
        for (int s = t; s < 4 * 2 * 64; s += 256) {
            const int ks = s >> 7, nt = (s >> 6) & 1, lane = s & 63;
            const int n = nt * 16 + (lane & 15);
            const int kb = ks * 32 + 8 * (lane >> 4);
            S8U h, m, lo;
            #pragma unroll
            for (int r = 0; r < 8; ++r) {
                const float a = gp2_w[(kb + r) * 32 + n];
                split3(a, h.u[r], m.u[r], lo.u[r]);
            }
            G2h[(ks * 2 + nt) * 64 + lane] = h.v;
            G2m[(ks * 2 + nt) * 64 + lane] = m.v;
            G2l[(ks * 2 + nt) * 64 + lane] = lo.v;
        }
    }
}

// ============================== main kernel ===============================
__global__ __launch_bounds__(256, 4)
void cag_main(const float* __restrict__ x, const float* __restrict__ ctx,
              const float* __restrict__ en_g, const float* __restrict__ en_b,
              const float* __restrict__ cpn_g, const float* __restrict__ cpn_b,
              const float* __restrict__ cp2_b,
              const float* __restrict__ ln1_g, const float* __restrict__ ln1_b,
              const float* __restrict__ gp2_b,
              const float* __restrict__ ln2_g, const float* __restrict__ ln2_b,
              const float* __restrict__ gp3_w, const float* __restrict__ gp3_b,
              const char* __restrict__ ws, float* __restrict__ out)
{
    // aliased region (33792 B):
    //   P0:  pbuf@0 (9216) + cfnbuf@12288 (9216)
    //   P1:  fragA buf0 @0 (12288) + cfnbuf@12288 (9216) + fragA buf1 @21504 (12288)
    //   epi: hbuf@0 (33792) / ibuf@0, lbuf@16384
    __shared__ __attribute__((aligned(16))) char smU[64 * 132 * 4];
    __shared__ float s_sc4[64][4];
    __shared__ float part_s[4][64];
    __shared__ float part_s2[4][64];
    __shared__ float s_ln1[64][2];
    __shared__ float s_cfs[64], s_cfs2[64];

    short (*fragA0)[4][64][8] = (short(*)[4][64][8])smU;            // 12288 B
    short (*fragA1)[4][64][8] = (short(*)[4][64][8])(smU + 21504);  // 12288 B
    float (*cfnbuf)[36] = (float(*)[36])(smU + 12288);              // 9216 B
    float (*pbuf)[36]   = (float(*)[36])smU;
    float (*hbuf)[132]  = (float(*)[132])smU;
    float (*ibuf)[36]   = (float(*)[36])smU;
    float (*lbuf)[20]   = (float(*)[20])(smU + 16384);

    const int tid = threadIdx.x;
    const int l = tid & 63, w = tid >> 6;
    const int sg = l >> 4, lr = l & 15;
    const int row0 = blockIdx.x * Rn;

    const s8v* A1h = (const s8v*)(ws + OFF_A1H);
    const s8v* A1m = (const s8v*)(ws + OFF_A1M);
    const s8v* A1l = (const s8v*)(ws + OFF_A1L);
    const s8v* C1h = (const s8v*)(ws + OFF_C1H);
    const s8v* C1m = (const s8v*)(ws + OFF_C1M);
    const s8v* C1l = (const s8v*)(ws + OFF_C1L);
    const s8v* C2h = (const s8v*)(ws + OFF_C2H);
    const s8v* C2m = (const s8v*)(ws + OFF_C2M);
    const s8v* C2l = (const s8v*)(ws + OFF_C2L);
    const s8v* G2h = (const s8v*)(ws + OFF_G2H);
    const s8v* G2m = (const s8v*)(ws + OFF_G2M);
    const s8v* G2l = (const s8v*)(ws + OFF_G2L);
    const float* Vpk = (const float*)(ws + OFF_VPK);
    const float* upk = (const float*)(ws + OFF_UPK);
    const float* cst = (const float*)(ws + OFF_CST);

    // ================= P0: context branch (wave-local MFMA) ================
    {
        const int crow = row0 + 16 * w + lr;
        const float* cb = ctx + (size_t)crow * 256 + 8 * sg;
        float cs = 0.f, cs2 = 0.f;
        vf4 ac0 = {0.f, 0.f, 0.f, 0.f}, ac1 = {0.f, 0.f, 0.f, 0.f};
        #pragma unroll
        for (int ks = 0; ks < 8; ++ks) {
            const float4 a0 = *(const float4*)(cb + ks * 32);
            const float4 a1 = *(const float4*)(cb + ks * 32 + 4);
            const float vv[8] = {a0.x, a0.y, a0.z, a0.w, a1.x, a1.y, a1.z, a1.w};
            #pragma unroll
            for (int j = 0; j < 8; ++j) { cs += vv[j]; cs2 = fmaf(vv[j], vv[j], cs2); }
            s8v ah, am, al;
            split3x8(vv, ah, am, al);
            mfma6(ac0, ah, am, al,
                  C1h[(ks * 2 + 0) * 64 + l], C1m[(ks * 2 + 0) * 64 + l], C1l[(ks * 2 + 0) * 64 + l]);
            mfma6(ac1, ah, am, al,
                  C1h[(ks * 2 + 1) * 64 + l], C1m[(ks * 2 + 1) * 64 + l], C1l[(ks * 2 + 1) * 64 + l]);
        }
        cs += __shfl_xor(cs, 16, 64); cs += __shfl_xor(cs, 32, 64);
        cs2 += __shfl_xor(cs2, 16, 64); cs2 += __shfl_xor(cs2, 32, 64);
        const float cm = cs * (1.f / 256.f);
        const float crr = rsqrtf(cs2 * (1.f / 256.f) - cm * cm + 1e-5f);
        float m_r[4], r_r[4];
        #pragma unroll
        for (int rg = 0; rg < 4; ++rg) {
            const int src = 4 * sg + rg;
            m_r[rg] = __shfl(cm, src, 64);
            r_r[rg] = __shfl(crr, src, 64);
        }
        #pragma unroll
        for (int ntl = 0; ntl < 2; ++ntl) {
            const int c = 16 * ntl + lr;
            const float u1 = upk[2 * c], u2 = upk[2 * c + 1];
            #pragma unroll
            for (int rg = 0; rg < 4; ++rg) {
                const float av = (ntl == 0) ? ac0[rg] : ac1[rg];
                const float a1v = r_r[rg] * av - r_r[rg] * m_r[rg] * u1 + u2;
                pbuf[16 * w + 4 * sg + rg][c] = gelu_f(a1v);
            }
        }
        __syncthreads();
        float pv[8];
        const int prow = 16 * w + lr;
        *(float4*)&pv[0] = *(const float4*)&pbuf[prow][8 * sg];
        *(float4*)&pv[4] = *(const float4*)&pbuf[prow][8 * sg + 4];
        s8v ph, pm_, pl;
        split3x8(pv, ph, pm_, pl);
        vf4 a20 = {0.f, 0.f, 0.f, 0.f}, a21 = {0.f, 0.f, 0.f, 0.f};
        mfma6(a20, ph, pm_, pl, C2h[0 * 64 + l], C2m[0 * 64 + l], C2l[0 * 64 + l]);
        mfma6(a21, ph, pm_, pl, C2h[1 * 64 + l], C2m[1 * 64 + l], C2l[1 * 64 + l]);
        const float cb0 = cp2_b[lr], cb1 = cp2_b[16 + lr];
        const float cg0 = cpn_g[lr], cg1 = cpn_g[16 + lr];
        const float cbb0 = cpn_b[lr], cbb1 = cpn_b[16 + lr];
        __syncthreads();
        #pragma unroll
        for (int rg = 0; rg < 4; ++rg) {
            const float v0 = a20[rg] + cb0, v1 = a21[rg] + cb1;
            float s = v0 + v1, s2 = v0 * v0 + v1 * v1;
            red16(s); red16(s2);
            const float pm = s * (1.f / 32.f);
            const float prs = rsqrtf(s2 * (1.f / 32.f) - pm * pm + 1e-5f);
            const float cn0 = (v0 - pm) * prs * cg0 + cbb0;
            const float cn1 = (v1 - pm) * prs * cg1 + cbb1;
            float t = cn0 + cn1, t2 = cn0 * cn0 + cn1 * cn1;
            red16(t); red16(t2);
            const int rr = 16 * w + 4 * sg + rg;
            if (lr == 0) { s_cfs[rr] = t; s_cfs2[rr] = t2; }
            cfnbuf[rr][lr] = cn0; cfnbuf[rr][16 + lr] = cn1;
        }
    }
    __syncthreads();   // cfn/s_cfs visible; pbuf dead; fragA region free

    // ================= P1: double-buffered phase GEMM over K=1056 ==========
    // One barrier per chunk: stage(ks) writes buf[ks&1]; mfma(ks) reads it.
    // stage(ks+1) overwrites buf[(ks-1)&1], which all waves finished reading
    // before passing barrier(ks) -> the post-mfma barrier is removable.
    vf4 acc[4][2];
    #pragma unroll
    for (int mt = 0; mt < 4; ++mt) { acc[mt][0] = vf4{0.f,0.f,0.f,0.f}; acc[mt][1] = vf4{0.f,0.f,0.f,0.f}; }

    float Sx = 0.f, Sxx = 0.f, Sxg = 0.f, Sxg2 = 0.f, Sxgb = 0.f, Sq = 0.f;

    const float* xb = x + (size_t)(row0 + 16 * w + lr) * 1024 + 8 * sg;
    const int nt0 = 2 * w;

    float4 xc0 = *(const float4*)(xb);
    float4 xc1 = *(const float4*)(xb + 4);
    float4 xn0, xn1;

    #pragma unroll 1
    for (int ks = 0; ks <= 32; ++ks) {
        short (*fA)[4][64][8] = (ks & 1) ? fragA1 : fragA0;
        // ---------- stage phase ----------
        const size_t q = (size_t)((ks * 8 + nt0) * 64 + l);
        const s8v B0h = A1h[q],      B0m = A1m[q],      B0l = A1l[q];
        const s8v B1h = A1h[q + 64], B1m = A1m[q + 64], B1l = A1l[q + 64];
        if (ks < 31) {
            xn0 = *(const float4*)(xb + (ks + 1) * 32);
            xn1 = *(const float4*)(xb + (ks + 1) * 32 + 4);
        }
        if (ks < 32) {
            const int kb = ks * 32 + 8 * sg;
            const float4 g0 = *(const float4*)(en_g + kb);
            const float4 g1 = *(const float4*)(en_g + kb + 4);
            const float4 e0 = *(const float4*)(en_b + kb);
            const float4 e1 = *(const float4*)(en_b + kb + 4);
            const float vv[8] = {xc0.x, xc0.y, xc0.z, xc0.w, xc1.x, xc1.y, xc1.z, xc1.w};
            const float gg[8] = {g0.x, g0.y, g0.z, g0.w, g1.x, g1.y, g1.z, g1.w};
            const float ee[8] = {e0.x, e0.y, e0.z, e0.w, e1.x, e1.y, e1.z, e1.w};
            #pragma unroll
            for (int j = 0; j < 8; ++j) {
                const float v = vv[j], g = gg[j], b = ee[j];
                Sx += v; Sxx = fmaf(v, v, Sxx);
                const float t = v * g;
                Sxg += t; Sxg2 = fmaf(t, g, Sxg2); Sxgb = fmaf(t, b, Sxgb); Sq = fmaf(t, t, Sq);
            }
            s8v H, M, L;
            split3x8(vv, H, M, L);
            *(s8v*)&fA[0][w][l][0] = H;
            *(s8v*)&fA[1][w][l][0] = M;
            *(s8v*)&fA[2][w][l][0] = L;
        } else {
            // finalize row stats + fused LN scalars
            float sx = Sx, sxx = Sxx, sxg = Sxg, sxg2 = Sxg2, sxgb = Sxgb, sq = Sq;
            #define RED2(s) { s += __shfl_xor(s, 16, 64); s += __shfl_xor(s, 32, 64); }
            RED2(sx) RED2(sxx) RED2(sxg) RED2(sxg2) RED2(sxgb) RED2(sq)
            #undef RED2
            const float xm = sx * (1.f / 1024.f);
            const float xvar = sxx * (1.f / 1024.f) - xm * xm;
            const float xr = rsqrtf(xvar + 1e-5f);
            const float xrinv = sqrtf(xvar + 1e-5f);
            const float Gs = cst[0], Bs = cst[1], Sg2c = cst[2], Sgbc = cst[3], Sb2c = cst[4];
            const float Semb = xr * (sxg - xm * Gs) + Bs;
            const float Semb2 = xr * xr * (sq - 2.f * xm * sxg2 + xm * xm * Sg2c)
                              + 2.f * xr * (sxgb - xm * Sgbc) + Sb2c;
            const int rr = 16 * w + lr;
            const float fm = (Semb + s_cfs[rr]) * (1.f / 1056.f);
            const float fvar = (Semb2 + s_cfs2[rr]) * (1.f / 1056.f) - fm * fm;
            const float fr = rsqrtf(fvar + 1e-5f);
            if (sg == 0) {
                s_sc4[rr][0] = fr * xr; s_sc4[rr][1] = -fr * xr * xm;
                s_sc4[rr][2] = fr;      s_sc4[rr][3] = -fr * fm;
            }
            // stage cf chunk (k=1024..1055), scaled by this row's sigma
            float vv[8];
            *(float4*)&vv[0] = *(const float4*)&cfnbuf[rr][8 * sg];
            *(float4*)&vv[4] = *(const float4*)&cfnbuf[rr][8 * sg + 4];
            #pragma unroll
            for (int j = 0; j < 8; ++j) vv[j] *= xrinv;
            s8v H, M, L;
            split3x8(vv, H, M, L);
            *(s8v*)&fA[0][w][l][0] = H;
            *(s8v*)&fA[1][w][l][0] = M;
            *(s8v*)&fA[2][w][l][0] = L;
        }
        // flush LDS writes, barrier; global loads stay in flight (no vmcnt drain)
        asm volatile("s_waitcnt lgkmcnt(0)\n\ts_barrier" ::: "memory");

        // ---------- mfma phase (no trailing barrier: double-buffered) ------
        __builtin_amdgcn_s_setprio(1);
        #pragma unroll
        for (int mt = 0; mt < 4; ++mt) {
            const s8v ah = *(const s8v*)&fA[0][mt][l][0];
            const s8v am = *(const s8v*)&fA[1][mt][l][0];
            const s8v al = *(const s8v*)&fA[2][mt][l][0];
            mfma6(acc[mt][0], ah, am, al, B0h, B0m, B0l);
            mfma6(acc[mt][1], ah, am, al, B1h, B1m, B1l);
        }
        __builtin_amdgcn_s_setprio(0);
        xc0 = xn0; xc1 = xn1;
    }

    // ================= epilogue: scalars + LN1 + gelu -> hbuf ==============
    {
        const int tc0 = 16 * (2 * w) + lr, tc1 = 16 * (2 * w + 1) + lr;
        float4 Vc[2];
        Vc[0] = *(const float4*)&Vpk[tc0 * 4];
        Vc[1] = *(const float4*)&Vpk[tc1 * 4];
        #pragma unroll
        for (int mt = 0; mt < 4; ++mt) {
            #pragma unroll
            for (int rg = 0; rg < 4; ++rg) {
                const float4 sc = *(const float4*)&s_sc4[16 * mt + 4 * sg + rg][0];
                #pragma unroll
                for (int ntl = 0; ntl < 2; ++ntl) {
                    acc[mt][ntl][rg] = sc.x * acc[mt][ntl][rg] + sc.y * Vc[ntl].x
                                     + sc.z * Vc[ntl].y + sc.w * Vc[ntl].z + Vc[ntl].w;
                }
            }
        }
        #pragma unroll
        for (int mt = 0; mt < 4; ++mt) {
            #pragma unroll
            for (int rg = 0; rg < 4; ++rg) {
                const float v0 = acc[mt][0][rg], v1 = acc[mt][1][rg];
                float s = v0 + v1, s2 = v0 * v0 + v1 * v1;
                red16(s); red16(s2);
                if (lr == 0) {
                    const int rr = 16 * mt + 4 * sg + rg;
                    part_s[w][rr] = s; part_s2[w][rr] = s2;
                }
            }
        }
        __syncthreads();
        if (tid < 64) {
            const float s = part_s[0][tid] + part_s[1][tid] + part_s[2][tid] + part_s[3][tid];
            const float s2 = part_s2[0][tid] + part_s2[1][tid] + part_s2[2][tid] + part_s2[3][tid];
            const float mn = s * (1.f / 128.f);
            s_ln1[tid][0] = mn;
            s_ln1[tid][1] = rsqrtf(s2 * (1.f / 128.f) - mn * mn + 1e-5f);
        }
        __syncthreads();
        float g1c[2], b1c[2];
        g1c[0] = ln1_g[tc0]; b1c[0] = ln1_b[tc0];
        g1c[1] = ln1_g[tc1]; b1c[1] = ln1_b[tc1];
        #pragma unroll
        for (int mt = 0; mt < 4; ++mt) {
            #pragma unroll
            for (int rg = 0; rg < 4; ++rg) {
                const int rr = 16 * mt + 4 * sg + rg;
                const float mn = s_ln1[rr][0], rs = s_ln1[rr][1];
                #pragma unroll
                for (int ntl = 0; ntl < 2; ++ntl) {
                    const float hp = gelu_f((acc[mt][ntl][rg] - mn) * rs * g1c[ntl] + b1c[ntl]);
                    hbuf[rr][16 * (2 * w + ntl) + lr] = hp;
                }
            }
        }
        __syncthreads();
    }

    // ================= P2: gp2 (128->32) + LN2 + gelu ======================
    float iv[2][4];
    {
        vf4 aG0 = {0.f, 0.f, 0.f, 0.f}, aG1 = {0.f, 0.f, 0.f, 0.f};
        const int hrow = 16 * w + lr;
        #pragma unroll
        for (int ks = 0; ks < 4; ++ks) {
            float pv[8];
            *(float4*)&pv[0] = *(const float4*)&hbuf[hrow][ks * 32 + 8 * sg];
            *(float4*)&pv[4] = *(const float4*)&hbuf[hrow][ks * 32 + 8 * sg + 4];
            s8v ah, am, al;
            split3x8(pv, ah, am, al);
            mfma6(aG0, ah, am, al,
                  G2h[(ks * 2 + 0) * 64 + l], G2m[(ks * 2 + 0) * 64 + l], G2l[(ks * 2 + 0) * 64 + l]);
            mfma6(aG1, ah, am, al,
                  G2h[(ks * 2 + 1) * 64 + l], G2m[(ks * 2 + 1) * 64 + l], G2l[(ks * 2 + 1) * 64 + l]);
        }
        const float gb0 = gp2_b[lr], gb1 = gp2_b[16 + lr];
        const float lg0 = ln2_g[lr], lg1 = ln2_g[16 + lr];
        const float lb0 = ln2_b[lr], lb1 = ln2_b[16 + lr];
        #pragma unroll
        for (int rg = 0; rg < 4; ++rg) {
            const float v0 = aG0[rg] + gb0, v1 = aG1[rg] + gb1;
            float s = v0 + v1, s2 = v0 * v0 + v1 * v1;
            red16(s); red16(s2);
            const float mn = s * (1.f / 32.f);
            const float rs = rsqrtf(s2 * (1.f / 32.f) - mn * mn + 1e-5f);
            iv[0][rg] = gelu_f((v0 - mn) * rs * lg0 + lb0);
            iv[1][rg] = gelu_f((v1 - mn) * rs * lg1 + lb1);
        }
    }
    __syncthreads();     // all hbuf reads done before ibuf overwrite
    #pragma unroll
    for (int rg = 0; rg < 4; ++rg) {
        const int rr = 16 * w + 4 * sg + rg;
        ibuf[rr][lr] = iv[0][rg];
        ibuf[rr][16 + lr] = iv[1][rg];
    }
    __syncthreads();

    // ================= P3: gp3 (32->16) + logits + top-2 ===================
    {
        const int r = tid >> 2, e4 = (tid & 3) * 4;
        float a0 = 0.f, a1 = 0.f, a2 = 0.f, a3 = 0.f;
        #pragma unroll 4
        for (int qq = 0; qq < 32; ++qq) {
            const float v = ibuf[r][qq];
            const float4 w3 = *(const float4*)(gp3_w + qq * 16 + e4);
            a0 = fmaf(v, w3.x, a0); a1 = fmaf(v, w3.y, a1);
            a2 = fmaf(v, w3.z, a2); a3 = fmaf(v, w3.w, a3);
        }
        const float4 b3 = *(const float4*)(gp3_b + e4);
        const float4 lg = make_float4(a0 + b3.x, a1 + b3.y, a2 + b3.z, a3 + b3.w);
        float* outl = out + (size_t)Bn * 4;
        *(float4*)(outl + (size_t)(row0 + r) * 16 + e4) = lg;
        *(float4*)&lbuf[r][e4] = lg;
    }
    __syncthreads();
    if (tid < 64) {
        float v[16];
        #pragma unroll
        for (int e = 0; e < 4; ++e) *(float4*)&v[e * 4] = *(const float4*)&lbuf[tid][e * 4];
        int i0 = 0; float v0 = v[0];
        #pragma unroll
        for (int e = 1; e < 16; ++e) if (v[e] > v0) { v0 = v[e]; i0 = e; }
        int i1 = -1; float v1 = -3.4e38f;
        #pragma unroll
        for (int e = 0; e < 16; ++e) if (e != i0 && v[e] > v1) { v1 = v[e]; i1 = e; }
        const float e1 = expf(v1 - v0);
        const float inv = 1.0f / (1.0f + e1);
        const size_t g = (size_t)(row0 + tid);
        out[g * 2 + 0] = inv;
        out[g * 2 + 1] = e1 * inv;
        float* outi = out + (size_t)Bn * 2;
        outi[g * 2 + 0] = (float)i0;
        outi[g * 2 + 1] = (float)i1;
    }
}

} // namespace

extern "C" void kernel_launch(void* const* d_in, const int* in_sizes, int n_in,
                              void* d_out, int out_size, void* d_ws, size_t ws_size,
                              hipStream_t stream) {
    const float* x     = (const float*)d_in[0];
    const float* ctx   = (const float*)d_in[1];
    const float* en_g  = (const float*)d_in[2];
    const float* en_b  = (const float*)d_in[3];
    const float* cn_g  = (const float*)d_in[4];
    const float* cn_b  = (const float*)d_in[5];
    const float* cp1_w = (const float*)d_in[6];
    const float* cp1_b = (const float*)d_in[7];
    const float* cp2_w = (const float*)d_in[8];
    const float* cp2_b = (const float*)d_in[9];
    const float* cpn_g = (const float*)d_in[10];
    const float* cpn_b = (const float*)d_in[11];
    const float* fn_g  = (const float*)d_in[12];
    const float* fn_b  = (const float*)d_in[13];
    const float* gp1_w = (const float*)d_in[14];
    const float* gp1_b = (const float*)d_in[15];
    const float* ln1_g = (const float*)d_in[16];
    const float* ln1_b = (const float*)d_in[17];
    const float* gp2_w = (const float*)d_in[18];
    const float* gp2_b = (const float*)d_in[19];
    const float* ln2_g = (const float*)d_in[20];
    const float* ln2_b = (const float*)d_in[21];
    const float* gp3_w = (const float*)d_in[22];
    const float* gp3_b = (const float*)d_in[23];

    char* ws = (char*)d_ws;
    hipLaunchKernelGGL(cag_prek1, dim3(33), dim3(256), 0, stream,
                       gp1_w, en_g, en_b, fn_g, fn_b, ws);
    hipLaunchKernelGGL(cag_prek2, dim3(4), dim3(256), 0, stream,
                       en_g, en_b, cn_g, cn_b, cp1_w, cp1_b, cp2_w, gp2_w, gp1_b, ws);
    hipLaunchKernelGGL(cag_main, dim3(Bn / Rn), dim3(256), 0, stream,
                       x, ctx, en_g, en_b, cpn_g, cpn_b, cp2_b,
                       ln1_g, ln1_b, gp2_b, ln2_g, ln2_b, gp3_w, gp3_b,
                       ws, (float*)d_out);
}

// Round 12
// 170.752 us; speedup vs baseline: 2.8349x; 1.1329x over previous
//
#include <hip/hip_runtime.h>
#include <math.h>

namespace {

using s8v = __attribute__((ext_vector_type(8))) short;
using vf4 = __attribute__((ext_vector_type(4))) float;

constexpr int Bn = 65536;
constexpr int Rn = 64;   // rows per block

// ---- workspace layout (bytes) ----
constexpr size_t OFF_A1H  = 0;        // 33*8*64*8 shorts = 270336 B each
constexpr size_t OFF_A1M  = 270336;
constexpr size_t OFF_A1L  = 540672;   // end 811008
constexpr size_t OFF_C1H  = 811008;   // 8*2*64*8 shorts = 16384 B each
constexpr size_t OFF_C1M  = 827392;
constexpr size_t OFF_C1L  = 843776;   // end 860160
constexpr size_t OFF_C2H  = 860160;   // 2*64*8 shorts = 2048 B each
constexpr size_t OFF_C2M  = 862208;
constexpr size_t OFF_C2L  = 864256;   // end 866304
constexpr size_t OFF_G2H  = 866304;   // 4*2*64*8 shorts = 8192 B each
constexpr size_t OFF_G2M  = 874496;
constexpr size_t OFF_G2L  = 882688;   // end 890880
constexpr size_t OFF_VPK  = 890880;   // float[128][4] = 2048 B
constexpr size_t OFF_UPK  = 892928;   // float[32][2] = 256 B
constexpr size_t OFF_CST  = 893184;   // float[8] = 32 B
constexpr size_t OFF_VPART= 893216;   // float[33][128][4] = 67584 B

__device__ __forceinline__ unsigned short bf16_rn(float f) {
    unsigned u = __float_as_uint(f);
    u += 0x7FFFu + ((u >> 16) & 1u);
    return (unsigned short)(u >> 16);
}
__device__ __forceinline__ float bf16_tof(unsigned short h) {
    return __uint_as_float(((unsigned)h) << 16);
}

union S8U { s8v v; unsigned short u[8]; };
union S8P { s8v v; unsigned u32[4]; };

__device__ __forceinline__ vf4 MFMA(s8v a, s8v b, vf4 c) {
    return __builtin_amdgcn_mfma_f32_16x16x32_bf16(a, b, c, 0, 0, 0);
}

// 6-product accumulate: exact x=(h+m+l), drops only (m,l),(l,m),(l,l) ~ 2^-26
__device__ __forceinline__ void mfma6(vf4& acc, s8v ah, s8v am, s8v al,
                                      s8v bh, s8v bm, s8v bl) {
    acc = MFMA(ah, bh, acc);
    acc = MFMA(ah, bm, acc);
    acc = MFMA(am, bh, acc);
    acc = MFMA(ah, bl, acc);
    acc = MFMA(al, bh, acc);
    acc = MFMA(am, bm, acc);
}

// scalar exact 3-way split (pre-kernels only)
__device__ __forceinline__ void split3(float v, unsigned short& h,
                                       unsigned short& m, unsigned short& l) {
    h = bf16_rn(v);
    const float r = v - bf16_tof(h);
    m = bf16_rn(r);
    const float r2 = r - bf16_tof(m);
    l = bf16_rn(r2);
}

// packed 3-way split of 8 fp32 via v_cvt_pk_bf16_f32 (RNE, == bf16_rn bits)
__device__ __forceinline__ void split3x8(const float* vv, s8v& H, s8v& M, s8v& L) {
    S8P h, m, l;
    #pragma unroll
    for (int p = 0; p < 4; ++p) {
        const float lo = vv[2 * p], hi = vv[2 * p + 1];
        unsigned ph, pm, pl;
        asm("v_cvt_pk_bf16_f32 %0, %1, %2" : "=v"(ph) : "v"(lo), "v"(hi));
        const float rlo = lo - __uint_as_float(ph << 16);
        const float rhi = hi - __uint_as_float(ph & 0xFFFF0000u);
        asm("v_cvt_pk_bf16_f32 %0, %1, %2" : "=v"(pm) : "v"(rlo), "v"(rhi));
        const float slo = rlo - __uint_as_float(pm << 16);
        const float shi = rhi - __uint_as_float(pm & 0xFFFF0000u);
        asm("v_cvt_pk_bf16_f32 %0, %1, %2" : "=v"(pl) : "v"(slo), "v"(shi));
        h.u32[p] = ph; m.u32[p] = pm; l.u32[p] = pl;
    }
    H = h.v; M = m.v; L = l.v;
}

__device__ __forceinline__ float gelu_f(float v) {
    return 0.5f * v * (1.0f + erff(v * 0.70710678118654752440f));
}

__device__ __forceinline__ void red16(float& s) {
    s += __shfl_xor(s, 1, 64); s += __shfl_xor(s, 2, 64);
    s += __shfl_xor(s, 4, 64); s += __shfl_xor(s, 8, 64);
}

// ======================= pre-kernel 1: pack big A (gp1) + V partials ======
__global__ void cag_prek1(const float* __restrict__ gp1_w,
                          const float* __restrict__ en_g, const float* __restrict__ en_b,
                          const float* __restrict__ fn_g, const float* __restrict__ fn_b,
                          char* __restrict__ ws)
{
    const int t = threadIdx.x, ch = blockIdx.x;
    s8v* A1h = (s8v*)(ws + OFF_A1H);
    s8v* A1m = (s8v*)(ws + OFF_A1M);
    s8v* A1l = (s8v*)(ws + OFF_A1L);
    float* Vpart = (float*)(ws + OFF_VPART);

    for (int s = t; s < 512; s += 256) {
        const int nt = s >> 6, lane = s & 63;
        const int n = nt * 16 + (lane & 15);
        const int jb = ch * 32 + 8 * (lane >> 4);
        S8U h, m, lo;
        #pragma unroll
        for (int r = 0; r < 8; ++r) {
            const int j = jb + r;
            const float sc = fn_g[j] * (j < 1024 ? en_g[j] : 1.0f);
            const float a = sc * gp1_w[(size_t)j * 128 + n];
            split3(a, h.u[r], m.u[r], lo.u[r]);
        }
        A1h[(ch * 8 + nt) * 64 + lane] = h.v;
        A1m[(ch * 8 + nt) * 64 + lane] = m.v;
        A1l[(ch * 8 + nt) * 64 + lane] = lo.v;
    }
    if (t < 128) {
        float v1 = 0.f, v2 = 0.f, v3 = 0.f, v4 = 0.f;
        for (int jj = 0; jj < 32; ++jj) {
            const int j = ch * 32 + jj;
            const float wv = gp1_w[(size_t)j * 128 + t];
            const float fg = fn_g[j];
            if (j < 1024) { v1 = fmaf(fg * en_g[j], wv, v1); v2 = fmaf(fg * en_b[j], wv, v2); }
            v3 = fmaf(fg, wv, v3);
            v4 = fmaf(fn_b[j], wv, v4);
        }
        float* p = Vpart + ((size_t)ch * 128 + t) * 4;
        p[0] = v1; p[1] = v2; p[2] = v3; p[3] = v4;
    }
}

// ======================= pre-kernel 2: V reduce, consts, small packs ======
__global__ void cag_prek2(const float* __restrict__ en_g, const float* __restrict__ en_b,
                          const float* __restrict__ cn_g, const float* __restrict__ cn_b,
                          const float* __restrict__ cp1_w, const float* __restrict__ cp1_b,
                          const float* __restrict__ cp2_w, const float* __restrict__ gp2_w,
                          const float* __restrict__ gp1_b,
                          char* __restrict__ ws)
{
    const int t = threadIdx.x, b = blockIdx.x;
    if (b == 0) {
        const float* Vpart = (const float*)(ws + OFF_VPART);
        float* Vpk = (float*)(ws + OFF_VPK);
        float* cst = (float*)(ws + OFF_CST);
        if (t < 128) {
            float v1 = 0.f, v2 = 0.f, v3 = 0.f, v4 = 0.f;
            for (int ch = 0; ch < 33; ++ch) {
                const float* p = Vpart + ((size_t)ch * 128 + t) * 4;
                v1 += p[0]; v2 += p[1]; v3 += p[2]; v4 += p[3];
            }
            v4 += gp1_b[t];
            float* q = Vpk + t * 4;
            q[0] = v1; q[1] = v2; q[2] = v3; q[3] = v4;
        }
        __shared__ float red[256];
        float part[5] = {0.f, 0.f, 0.f, 0.f, 0.f};
        for (int i = t; i < 1024; i += 256) {
            const float g = en_g[i], bb = en_b[i];
            part[0] += g; part[1] += bb; part[2] += g * g; part[3] += g * bb; part[4] += bb * bb;
        }
        for (int f = 0; f < 5; ++f) {
            red[t] = part[f]; __syncthreads();
            for (int s = 128; s > 0; s >>= 1) { if (t < s) red[t] += red[t + s]; __syncthreads(); }
            if (t == 0) cst[f] = red[0];
            __syncthreads();
        }
    } else if (b == 1) {
        s8v* C1h = (s8v*)(ws + OFF_C1H);
        s8v* C1m = (s8v*)(ws + OFF_C1M);
        s8v* C1l = (s8v*)(ws + OFF_C1L);
        float* up = (float*)(ws + OFF_UPK);
        for (int s = t; s < 8 * 2 * 64; s += 256) {
            const int ks = s >> 7, nt = (s >> 6) & 1, lane = s & 63;
            const int n = nt * 16 + (lane & 15);
            const int kb = ks * 32 + 8 * (lane >> 4);
            S8U h, m, lo;
            #pragma unroll
            for (int r = 0; r < 8; ++r) {
                const int k = kb + r;
                const float a = cn_g[k] * cp1_w[k * 32 + n];
                split3(a, h.u[r], m.u[r], lo.u[r]);
            }
            C1h[(ks * 2 + nt) * 64 + lane] = h.v;
            C1m[(ks * 2 + nt) * 64 + lane] = m.v;
            C1l[(ks * 2 + nt) * 64 + lane] = lo.v;
        }
        if (t < 32) {
            float u1 = 0.f, u2 = 0.f;
            for (int c = 0; c < 256; ++c) {
                u1 = fmaf(cn_g[c], cp1_w[c * 32 + t], u1);
                u2 = fmaf(cn_b[c], cp1_w[c * 32 + t], u2);
            }
            up[2 * t] = u1; up[2 * t + 1] = u2 + cp1_b[t];
        }
    } else if (b == 2) {
        s8v* C2h = (s8v*)(ws + OFF_C2H);
        s8v* C2m = (s8v*)(ws + OFF_C2M);
        s8v* C2l = (s8v*)(ws + OFF_C2L);
        if (t < 128) {
            const int nt = t >> 6, lane = t & 63;
            const int n = nt * 16 + (lane & 15);
            const int kb = 8 * (lane >> 4);
            S8U h, m, lo;
            #pragma unroll
            for (int r = 0; r < 8; ++r) {
                const float a = cp2_w[(kb + r) * 32 + n];
                split3(a, h.u[r], m.u[r], lo.u[r]);
            }
            C2h[nt * 64 + lane] = h.v;
            C2m[nt * 64 + lane] = m.v;
            C2l[nt * 64 + lane] = lo.v;
        }
    } else {
        s8v* G2h = (s8v*)(ws + OFF_G2H);
        s8v* G2m = (s8v*)(ws + OFF_G2M);
        s8v* G2l = (s8v*)(ws + OFF_G2L);
        for (int s = t; s < 4 * 2 * 64; s += 256) {
            const int ks = s >> 7, nt = (s >> 6) & 1, lane = s & 63;
            const int n = nt * 16 + (lane & 15);
            const int kb = ks * 32 + 8 * (lane >> 4);
            S8U h, m, lo;
            #pragma unroll
            for (int r = 0; r < 8; ++r) {
                const float a = gp2_w[(kb + r) * 32 + n];
                split3(a, h.u[r], m.u[r], lo.u[r]);
            }
            G2h[(ks * 2 + nt) * 64 + lane] = h.v;
            G2m[(ks * 2 + nt) * 64 + lane] = m.v;
            G2l[(ks * 2 + nt) * 64 + lane] = lo.v;
        }
    }
}

// ============================== main kernel ===============================
__global__ __launch_bounds__(256, 4)
void cag_main(const float* __restrict__ x, const float* __restrict__ ctx,
              const float* __restrict__ en_g, const float* __restrict__ en_b,
              const float* __restrict__ cpn_g, const float* __restrict__ cpn_b,
              const float* __restrict__ cp2_b,
              const float* __restrict__ ln1_g, const float* __restrict__ ln1_b,
              const float* __restrict__ gp2_b,
              const float* __restrict__ ln2_g, const float* __restrict__ ln2_b,
              const float* __restrict__ gp3_w, const float* __restrict__ gp3_b,
              const char* __restrict__ ws, float* __restrict__ out)
{
    // aliased region (33792 B):
    //   P0:  pbuf@0 (9216) + cfnbuf@12288 (9216) + enbuf@21504 (8192)
    //   P1:  fragA@0 (12288) + cfnbuf@12288 (9216) + enbuf@21504 (8192)
    //   epi: hbuf@0 (33792) / ibuf@0, lbuf@16384
    __shared__ __attribute__((aligned(16))) char smU[64 * 132 * 4];
    __shared__ float s_sc4[64][4];
    __shared__ float part_s[4][64];
    __shared__ float part_s2[4][64];
    __shared__ float s_ln1[64][2];
    __shared__ float s_cfs[64], s_cfs2[64];

    short (*fragA)[4][64][8] = (short(*)[4][64][8])smU;           // [3][4][64][8] = 12288 B
    float (*cfnbuf)[36] = (float(*)[36])(smU + 12288);            // 9216 B
    float* enbuf_g      = (float*)(smU + 21504);                  // 4096 B (1024 f)
    float* enbuf_b      = (float*)(smU + 21504 + 4096);           // 4096 B (1024 f)
    float (*pbuf)[36]   = (float(*)[36])smU;
    float (*hbuf)[132]  = (float(*)[132])smU;
    float (*ibuf)[36]   = (float(*)[36])smU;
    float (*lbuf)[20]   = (float(*)[20])(smU + 16384);

    const int tid = threadIdx.x;
    const int l = tid & 63, w = tid >> 6;
    const int sg = l >> 4, lr = l & 15;
    const int row0 = blockIdx.x * Rn;

    const s8v* A1h = (const s8v*)(ws + OFF_A1H);
    const s8v* A1m = (const s8v*)(ws + OFF_A1M);
    const s8v* A1l = (const s8v*)(ws + OFF_A1L);
    const s8v* C1h = (const s8v*)(ws + OFF_C1H);
    const s8v* C1m = (const s8v*)(ws + OFF_C1M);
    const s8v* C1l = (const s8v*)(ws + OFF_C1L);
    const s8v* C2h = (const s8v*)(ws + OFF_C2H);
    const s8v* C2m = (const s8v*)(ws + OFF_C2M);
    const s8v* C2l = (const s8v*)(ws + OFF_C2L);
    const s8v* G2h = (const s8v*)(ws + OFF_G2H);
    const s8v* G2m = (const s8v*)(ws + OFF_G2M);
    const s8v* G2l = (const s8v*)(ws + OFF_G2L);
    const float* Vpk = (const float*)(ws + OFF_VPK);
    const float* upk = (const float*)(ws + OFF_UPK);
    const float* cst = (const float*)(ws + OFF_CST);

    // ---- preload en_g/en_b into LDS (covered by P0; visible after its
    //      first __syncthreads). 1024 floats each = 256 float4 per array.
    {
        ((float4*)enbuf_g)[tid] = ((const float4*)en_g)[tid];
        ((float4*)enbuf_b)[tid] = ((const float4*)en_b)[tid];
    }

    // ================= P0: context branch (wave-local MFMA) ================
    {
        const int crow = row0 + 16 * w + lr;
        const float* cb = ctx + (size_t)crow * 256 + 8 * sg;
        float cs = 0.f, cs2 = 0.f;
        vf4 ac0 = {0.f, 0.f, 0.f, 0.f}, ac1 = {0.f, 0.f, 0.f, 0.f};
        #pragma unroll
        for (int ks = 0; ks < 8; ++ks) {
            const float4 a0 = *(const float4*)(cb + ks * 32);
            const float4 a1 = *(const float4*)(cb + ks * 32 + 4);
            const float vv[8] = {a0.x, a0.y, a0.z, a0.w, a1.x, a1.y, a1.z, a1.w};
            #pragma unroll
            for (int j = 0; j < 8; ++j) { cs += vv[j]; cs2 = fmaf(vv[j], vv[j], cs2); }
            s8v ah, am, al;
            split3x8(vv, ah, am, al);
            mfma6(ac0, ah, am, al,
                  C1h[(ks * 2 + 0) * 64 + l], C1m[(ks * 2 + 0) * 64 + l], C1l[(ks * 2 + 0) * 64 + l]);
            mfma6(ac1, ah, am, al,
                  C1h[(ks * 2 + 1) * 64 + l], C1m[(ks * 2 + 1) * 64 + l], C1l[(ks * 2 + 1) * 64 + l]);
        }
        cs += __shfl_xor(cs, 16, 64); cs += __shfl_xor(cs, 32, 64);
        cs2 += __shfl_xor(cs2, 16, 64); cs2 += __shfl_xor(cs2, 32, 64);
        const float cm = cs * (1.f / 256.f);
        const float crr = rsqrtf(cs2 * (1.f / 256.f) - cm * cm + 1e-5f);
        float m_r[4], r_r[4];
        #pragma unroll
        for (int rg = 0; rg < 4; ++rg) {
            const int src = 4 * sg + rg;
            m_r[rg] = __shfl(cm, src, 64);
            r_r[rg] = __shfl(crr, src, 64);
        }
        #pragma unroll
        for (int ntl = 0; ntl < 2; ++ntl) {
            const int c = 16 * ntl + lr;
            const float u1 = upk[2 * c], u2 = upk[2 * c + 1];
            #pragma unroll
            for (int rg = 0; rg < 4; ++rg) {
                const float av = (ntl == 0) ? ac0[rg] : ac1[rg];
                const float a1v = r_r[rg] * av - r_r[rg] * m_r[rg] * u1 + u2;
                pbuf[16 * w + 4 * sg + rg][c] = gelu_f(a1v);
            }
        }
        __syncthreads();
        float pv[8];
        const int prow = 16 * w + lr;
        *(float4*)&pv[0] = *(const float4*)&pbuf[prow][8 * sg];
        *(float4*)&pv[4] = *(const float4*)&pbuf[prow][8 * sg + 4];
        s8v ph, pm_, pl;
        split3x8(pv, ph, pm_, pl);
        vf4 a20 = {0.f, 0.f, 0.f, 0.f}, a21 = {0.f, 0.f, 0.f, 0.f};
        mfma6(a20, ph, pm_, pl, C2h[0 * 64 + l], C2m[0 * 64 + l], C2l[0 * 64 + l]);
        mfma6(a21, ph, pm_, pl, C2h[1 * 64 + l], C2m[1 * 64 + l], C2l[1 * 64 + l]);
        const float cb0 = cp2_b[lr], cb1 = cp2_b[16 + lr];
        const float cg0 = cpn_g[lr], cg1 = cpn_g[16 + lr];
        const float cbb0 = cpn_b[lr], cbb1 = cpn_b[16 + lr];
        __syncthreads();
        #pragma unroll
        for (int rg = 0; rg < 4; ++rg) {
            const float v0 = a20[rg] + cb0, v1 = a21[rg] + cb1;
            float s = v0 + v1, s2 = v0 * v0 + v1 * v1;
            red16(s); red16(s2);
            const float pm = s * (1.f / 32.f);
            const float prs = rsqrtf(s2 * (1.f / 32.f) - pm * pm + 1e-5f);
            const float cn0 = (v0 - pm) * prs * cg0 + cbb0;
            const float cn1 = (v1 - pm) * prs * cg1 + cbb1;
            float t = cn0 + cn1, t2 = cn0 * cn0 + cn1 * cn1;
            red16(t); red16(t2);
            const int rr = 16 * w + 4 * sg + rg;
            if (lr == 0) { s_cfs[rr] = t; s_cfs2[rr] = t2; }
            cfnbuf[rr][lr] = cn0; cfnbuf[rr][16 + lr] = cn1;
        }
    }
    __syncthreads();   // cfn/s_cfs/enbuf visible; pbuf dead; fragA region free

    // ================= P1: phase-split GEMM over K=1056 ====================
    vf4 acc[4][2];
    #pragma unroll
    for (int mt = 0; mt < 4; ++mt) { acc[mt][0] = vf4{0.f,0.f,0.f,0.f}; acc[mt][1] = vf4{0.f,0.f,0.f,0.f}; }

    float Sx = 0.f, Sxx = 0.f, Sxg = 0.f, Sxg2 = 0.f, Sxgb = 0.f, Sq = 0.f;

    const float* xb = x + (size_t)(row0 + 16 * w + lr) * 1024 + 8 * sg;
    const int nt0 = 2 * w;

    float4 xc0 = *(const float4*)(xb);
    float4 xc1 = *(const float4*)(xb + 4);
    float4 xn0, xn1;

    #pragma unroll 1
    for (int ks = 0; ks <= 32; ++ks) {
        // ---------- stage phase ----------
        // B loads for THIS ks (L2) — in flight across stage + barrier
        const size_t q = (size_t)((ks * 8 + nt0) * 64 + l);
        const s8v B0h = A1h[q],      B0m = A1m[q],      B0l = A1l[q];
        const s8v B1h = A1h[q + 64], B1m = A1m[q + 64], B1l = A1l[q + 64];
        // x prefetch for ks+1 (HBM) — in flight across stage + mfma phases
        if (ks < 31) {
            xn0 = *(const float4*)(xb + (ks + 1) * 32);
            xn1 = *(const float4*)(xb + (ks + 1) * 32 + 4);
        }
        if (ks < 32) {
            const int kb = ks * 32 + 8 * sg;
            // g/e from LDS (lgkm counter — decoupled from vmem chain)
            const float4 g0 = *(const float4*)(enbuf_g + kb);
            const float4 g1 = *(const float4*)(enbuf_g + kb + 4);
            const float4 e0 = *(const float4*)(enbuf_b + kb);
            const float4 e1 = *(const float4*)(enbuf_b + kb + 4);
            const float vv[8] = {xc0.x, xc0.y, xc0.z, xc0.w, xc1.x, xc1.y, xc1.z, xc1.w};
            const float gg[8] = {g0.x, g0.y, g0.z, g0.w, g1.x, g1.y, g1.z, g1.w};
            const float ee[8] = {e0.x, e0.y, e0.z, e0.w, e1.x, e1.y, e1.z, e1.w};
            #pragma unroll
            for (int j = 0; j < 8; ++j) {
                const float v = vv[j], g = gg[j], b = ee[j];
                Sx += v; Sxx = fmaf(v, v, Sxx);
                const float t = v * g;
                Sxg += t; Sxg2 = fmaf(t, g, Sxg2); Sxgb = fmaf(t, b, Sxgb); Sq = fmaf(t, t, Sq);
            }
            s8v H, M, L;
            split3x8(vv, H, M, L);
            *(s8v*)&fragA[0][w][l][0] = H;
            *(s8v*)&fragA[1][w][l][0] = M;
            *(s8v*)&fragA[2][w][l][0] = L;
        } else {
            // finalize row stats + fused LN scalars
            float sx = Sx, sxx = Sxx, sxg = Sxg, sxg2 = Sxg2, sxgb = Sxgb, sq = Sq;
            #define RED2(s) { s += __shfl_xor(s, 16, 64); s += __shfl_xor(s, 32, 64); }
            RED2(sx) RED2(sxx) RED2(sxg) RED2(sxg2) RED2(sxgb) RED2(sq)
            #undef RED2
            const float xm = sx * (1.f / 1024.f);
            const float xvar = sxx * (1.f / 1024.f) - xm * xm;
            const float xr = rsqrtf(xvar + 1e-5f);
            const float xrinv = sqrtf(xvar + 1e-5f);
            const float Gs = cst[0], Bs = cst[1], Sg2c = cst[2], Sgbc = cst[3], Sb2c = cst[4];
            const float Semb = xr * (sxg - xm * Gs) + Bs;
            const float Semb2 = xr * xr * (sq - 2.f * xm * sxg2 + xm * xm * Sg2c)
                              + 2.f * xr * (sxgb - xm * Sgbc) + Sb2c;
            const int rr = 16 * w + lr;
            const float fm = (Semb + s_cfs[rr]) * (1.f / 1056.f);
            const float fvar = (Semb2 + s_cfs2[rr]) * (1.f / 1056.f) - fm * fm;
            const float fr = rsqrtf(fvar + 1e-5f);
            if (sg == 0) {
                s_sc4[rr][0] = fr * xr; s_sc4[rr][1] = -fr * xr * xm;
                s_sc4[rr][2] = fr;      s_sc4[rr][3] = -fr * fm;
            }
            // stage cf chunk (k=1024..1055), scaled by this row's sigma
            float vv[8];
            *(float4*)&vv[0] = *(const float4*)&cfnbuf[rr][8 * sg];
            *(float4*)&vv[4] = *(const float4*)&cfnbuf[rr][8 * sg + 4];
            #pragma unroll
            for (int j = 0; j < 8; ++j) vv[j] *= xrinv;
            s8v H, M, L;
            split3x8(vv, H, M, L);
            *(s8v*)&fragA[0][w][l][0] = H;
            *(s8v*)&fragA[1][w][l][0] = M;
            *(s8v*)&fragA[2][w][l][0] = L;
        }
        // flush LDS writes, barrier; global loads stay in flight (no vmcnt drain)
        asm volatile("s_waitcnt lgkmcnt(0)\n\ts_barrier" ::: "memory");

        // ---------- mfma phase ----------
        __builtin_amdgcn_s_setprio(1);
        #pragma unroll
        for (int mt = 0; mt < 4; ++mt) {
            const s8v ah = *(const s8v*)&fragA[0][mt][l][0];
            const s8v am = *(const s8v*)&fragA[1][mt][l][0];
            const s8v al = *(const s8v*)&fragA[2][mt][l][0];
            mfma6(acc[mt][0], ah, am, al, B0h, B0m, B0l);
            mfma6(acc[mt][1], ah, am, al, B1h, B1m, B1l);
        }
        __builtin_amdgcn_s_setprio(0);
        asm volatile("s_barrier" ::: "memory");
        xc0 = xn0; xc1 = xn1;
    }

    // ================= epilogue: scalars + LN1 + gelu -> hbuf ==============
    {
        const int tc0 = 16 * (2 * w) + lr, tc1 = 16 * (2 * w + 1) + lr;
        float4 Vc[2];
        Vc[0] = *(const float4*)&Vpk[tc0 * 4];
        Vc[1] = *(const float4*)&Vpk[tc1 * 4];
        #pragma unroll
        for (int mt = 0; mt < 4; ++mt) {
            #pragma unroll
            for (int rg = 0; rg < 4; ++rg) {
                const float4 sc = *(const float4*)&s_sc4[16 * mt + 4 * sg + rg][0];
                #pragma unroll
                for (int ntl = 0; ntl < 2; ++ntl) {
                    acc[mt][ntl][rg] = sc.x * acc[mt][ntl][rg] + sc.y * Vc[ntl].x
                                     + sc.z * Vc[ntl].y + sc.w * Vc[ntl].z + Vc[ntl].w;
                }
            }
        }
        #pragma unroll
        for (int mt = 0; mt < 4; ++mt) {
            #pragma unroll
            for (int rg = 0; rg < 4; ++rg) {
                const float v0 = acc[mt][0][rg], v1 = acc[mt][1][rg];
                float s = v0 + v1, s2 = v0 * v0 + v1 * v1;
                red16(s); red16(s2);
                if (lr == 0) {
                    const int rr = 16 * mt + 4 * sg + rg;
                    part_s[w][rr] = s; part_s2[w][rr] = s2;
                }
            }
        }
        __syncthreads();
        if (tid < 64) {
            const float s = part_s[0][tid] + part_s[1][tid] + part_s[2][tid] + part_s[3][tid];
            const float s2 = part_s2[0][tid] + part_s2[1][tid] + part_s2[2][tid] + part_s2[3][tid];
            const float mn = s * (1.f / 128.f);
            s_ln1[tid][0] = mn;
            s_ln1[tid][1] = rsqrtf(s2 * (1.f / 128.f) - mn * mn + 1e-5f);
        }
        __syncthreads();
        float g1c[2], b1c[2];
        g1c[0] = ln1_g[tc0]; b1c[0] = ln1_b[tc0];
        g1c[1] = ln1_g[tc1]; b1c[1] = ln1_b[tc1];
        #pragma unroll
        for (int mt = 0; mt < 4; ++mt) {
            #pragma unroll
            for (int rg = 0; rg < 4; ++rg) {
                const int rr = 16 * mt + 4 * sg + rg;
                const float mn = s_ln1[rr][0], rs = s_ln1[rr][1];
                #pragma unroll
                for (int ntl = 0; ntl < 2; ++ntl) {
                    const float hp = gelu_f((acc[mt][ntl][rg] - mn) * rs * g1c[ntl] + b1c[ntl]);
                    hbuf[rr][16 * (2 * w + ntl) + lr] = hp;
                }
            }
        }
        __syncthreads();
    }

    // ================= P2: gp2 (128->32) + LN2 + gelu ======================
    float iv[2][4];
    {
        vf4 aG0 = {0.f, 0.f, 0.f, 0.f}, aG1 = {0.f, 0.f, 0.f, 0.f};
        const int hrow = 16 * w + lr;
        #pragma unroll
        for (int ks = 0; ks < 4; ++ks) {
            float pv[8];
            *(float4*)&pv[0] = *(const float4*)&hbuf[hrow][ks * 32 + 8 * sg];
            *(float4*)&pv[4] = *(const float4*)&hbuf[hrow][ks * 32 + 8 * sg + 4];
            s8v ah, am, al;
            split3x8(pv, ah, am, al);
            mfma6(aG0, ah, am, al,
                  G2h[(ks * 2 + 0) * 64 + l], G2m[(ks * 2 + 0) * 64 + l], G2l[(ks * 2 + 0) * 64 + l]);
            mfma6(aG1, ah, am, al,
                  G2h[(ks * 2 + 1) * 64 + l], G2m[(ks * 2 + 1) * 64 + l], G2l[(ks * 2 + 1) * 64 + l]);
        }
        const float gb0 = gp2_b[lr], gb1 = gp2_b[16 + lr];
        const float lg0 = ln2_g[lr], lg1 = ln2_g[16 + lr];
        const float lb0 = ln2_b[lr], lb1 = ln2_b[16 + lr];
        #pragma unroll
        for (int rg = 0; rg < 4; ++rg) {
            const float v0 = aG0[rg] + gb0, v1 = aG1[rg] + gb1;
            float s = v0 + v1, s2 = v0 * v0 + v1 * v1;
            red16(s); red16(s2);
            const float mn = s * (1.f / 32.f);
            const float rs = rsqrtf(s2 * (1.f / 32.f) - mn * mn + 1e-5f);
            iv[0][rg] = gelu_f((v0 - mn) * rs * lg0 + lb0);
            iv[1][rg] = gelu_f((v1 - mn) * rs * lg1 + lb1);
        }
    }
    __syncthreads();     // all hbuf reads done before ibuf overwrite
    #pragma unroll
    for (int rg = 0; rg < 4; ++rg) {
        const int rr = 16 * w + 4 * sg + rg;
        ibuf[rr][lr] = iv[0][rg];
        ibuf[rr][16 + lr] = iv[1][rg];
    }
    __syncthreads();

    // ================= P3: gp3 (32->16) + logits + top-2 ===================
    {
        const int r = tid >> 2, e4 = (tid & 3) * 4;
        float a0 = 0.f, a1 = 0.f, a2 = 0.f, a3 = 0.f;
        #pragma unroll 4
        for (int qq = 0; qq < 32; ++qq) {
            const float v = ibuf[r][qq];
            const float4 w3 = *(const float4*)(gp3_w + qq * 16 + e4);
            a0 = fmaf(v, w3.x, a0); a1 = fmaf(v, w3.y, a1);
            a2 = fmaf(v, w3.z, a2); a3 = fmaf(v, w3.w, a3);
        }
        const float4 b3 = *(const float4*)(gp3_b + e4);
        const float4 lg = make_float4(a0 + b3.x, a1 + b3.y, a2 + b3.z, a3 + b3.w);
        float* outl = out + (size_t)Bn * 4;
        *(float4*)(outl + (size_t)(row0 + r) * 16 + e4) = lg;
        *(float4*)&lbuf[r][e4] = lg;
    }
    __syncthreads();
    if (tid < 64) {
        float v[16];
        #pragma unroll
        for (int e = 0; e < 4; ++e) *(float4*)&v[e * 4] = *(const float4*)&lbuf[tid][e * 4];
        int i0 = 0; float v0 = v[0];
        #pragma unroll
        for (int e = 1; e < 16; ++e) if (v[e] > v0) { v0 = v[e]; i0 = e; }
        int i1 = -1; float v1 = -3.4e38f;
        #pragma unroll
        for (int e = 0; e < 16; ++e) if (e != i0 && v[e] > v1) { v1 = v[e]; i1 = e; }
        const float e1 = expf(v1 - v0);
        const float inv = 1.0f / (1.0f + e1);
        const size_t g = (size_t)(row0 + tid);
        out[g * 2 + 0] = inv;
        out[g * 2 + 1] = e1 * inv;
        float* outi = out + (size_t)Bn * 2;
        outi[g * 2 + 0] = (float)i0;
        outi[g * 2 + 1] = (float)i1;
    }
}

} // namespace

extern "C" void kernel_launch(void* const* d_in, const int* in_sizes, int n_in,
                              void* d_out, int out_size, void* d_ws, size_t ws_size,
                              hipStream_t stream) {
    const float* x     = (const float*)d_in[0];
    const float* ctx   = (const float*)d_in[1];
    const float* en_g  = (const float*)d_in[2];
    const float* en_b  = (const float*)d_in[3];
    const float* cn_g  = (const float*)d_in[4];
    const float* cn_b  = (const float*)d_in[5];
    const float* cp1_w = (const float*)d_in[6];
    const float* cp1_b = (const float*)d_in[7];
    const float* cp2_w = (const float*)d_in[8];
    const float* cp2_b = (const float*)d_in[9];
    const float* cpn_g = (const float*)d_in[10];
    const float* cpn_b = (const float*)d_in[11];
    const float* fn_g  = (const float*)d_in[12];
    const float* fn_b  = (const float*)d_in[13];
    const float* gp1_w = (const float*)d_in[14];
    const float* gp1_b = (const float*)d_in[15];
    const float* ln1_g = (const float*)d_in[16];
    const float* ln1_b = (const float*)d_in[17];
    const float* gp2_w = (const float*)d_in[18];
    const float* gp2_b = (const float*)d_in[19];
    const float* ln2_g = (const float*)d_in[20];
    const float* ln2_b = (const float*)d_in[21];
    const float* gp3_w = (const float*)d_in[22];
    const float* gp3_b = (const float*)d_in[23];

    char* ws = (char*)d_ws;
    hipLaunchKernelGGL(cag_prek1, dim3(33), dim3(256), 0, stream,
                       gp1_w, en_g, en_b, fn_g, fn_b, ws);
    hipLaunchKernelGGL(cag_prek2, dim3(4), dim3(256), 0, stream,
                       en_g, en_b, cn_g, cn_b, cp1_w, cp1_b, cp2_w, gp2_w, gp1_b, ws);
    hipLaunchKernelGGL(cag_main, dim3(Bn / Rn), dim3(256), 0, stream,
                       x, ctx, en_g, en_b, cpn_g, cpn_b, cp2_b,
                       ln1_g, ln1_b, gp2_b, ln2_g, ln2_b, gp3_w, gp3_b,
                       ws, (float*)d_out);
}